// Round 1
// baseline (1369.480 us; speedup 1.0000x reference)
//
#include <hip/hip_runtime.h>

#define N_NODES 20000
#define N_EDGES 320000
#define HD 128
#define FIN 162      // 24 + 10 + 128
#define KE 260       // 2*H + ETN

__device__ __forceinline__ float leaky(float x){ return x > 0.f ? x : 0.01f*x; }
// monotone float->uint mapping: order-preserving for all finite floats
__device__ __forceinline__ unsigned fmap(float f){
    unsigned u = __float_as_uint(f);
    return (u & 0x80000000u) ? ~u : (u | 0x80000000u);
}
__device__ __forceinline__ float funmap(unsigned u){
    return __uint_as_float((u & 0x80000000u) ? (u & 0x7fffffffu) : ~u);
}
__device__ __forceinline__ unsigned umax_(unsigned a, unsigned b){ return a > b ? a : b; }

// ---------------------------------------------------------------------------
// cf = (child_feats @ op_w.T + op_b) * exists  ; ipf0_m = mapped colmax(cf)
// ---------------------------------------------------------------------------
__global__ __launch_bounds__(256) void encode_nodes(
    const float* __restrict__ feats,    // [N,162]
    const float* __restrict__ exists,   // [N]
    const float* __restrict__ W,        // [128,162]
    const float* __restrict__ bvec,     // [128]
    float* __restrict__ cf,             // [N,128] out
    unsigned* __restrict__ ipf0_m)      // [128] mapped-uint accum (init 0)
{
    __shared__ float As[16][128];
    __shared__ float Bs[16][128];
    __shared__ float As2[2][128];
    __shared__ float Bs2[2][128];
    __shared__ float ex_s[128];
    __shared__ unsigned colmax[128];
    const int t  = threadIdx.x;
    const int tx = t & 15, ty = t >> 4;
    const int base = blockIdx.x * 128;

    if (t < 128) {
        int n = base + t; if (n >= N_NODES) n = N_NODES - 1;
        ex_s[t] = exists[n];
        colmax[t] = 0u;
        // K tail (k = 160,161)
        float2 v = *(const float2*)&feats[n*FIN + 160];
        As2[0][t] = v.x; As2[1][t] = v.y;
        float2 w = *(const float2*)&W[t*FIN + 160];
        Bs2[0][t] = w.x; Bs2[1][t] = w.y;
    }

    float acc[8][8];
    #pragma unroll
    for (int i = 0; i < 8; ++i)
        #pragma unroll
        for (int j = 0; j < 8; ++j) acc[i][j] = 0.f;

    for (int c = 0; c < 10; ++c) {
        const int kk = c * 16;
        __syncthreads();
        #pragma unroll
        for (int l = 0; l < 4; ++l) {               // A: 128x16 via float2
            int idx = l*256 + t;                    // 0..1023
            int m = idx & 127, kh = idx >> 7;       // kh 0..7
            int n = base + m; if (n >= N_NODES) n = N_NODES - 1;
            float2 v = *(const float2*)&feats[n*FIN + kk + kh*2];
            As[kh*2+0][m] = v.x; As[kh*2+1][m] = v.y;
        }
        #pragma unroll
        for (int l = 0; l < 4; ++l) {               // B: 16x128 via float2
            int idx = l*256 + t;
            int h = idx & 127, kh = idx >> 7;
            float2 v = *(const float2*)&W[h*FIN + kk + kh*2];
            Bs[kh*2+0][h] = v.x; Bs[kh*2+1][h] = v.y;
        }
        __syncthreads();
        #pragma unroll
        for (int k = 0; k < 16; ++k) {
            float4 a0 = *(const float4*)&As[k][ty*8];
            float4 a1 = *(const float4*)&As[k][ty*8+4];
            float4 b0 = *(const float4*)&Bs[k][tx*8];
            float4 b1 = *(const float4*)&Bs[k][tx*8+4];
            float av[8] = {a0.x,a0.y,a0.z,a0.w,a1.x,a1.y,a1.z,a1.w};
            float bv[8] = {b0.x,b0.y,b0.z,b0.w,b1.x,b1.y,b1.z,b1.w};
            #pragma unroll
            for (int i = 0; i < 8; ++i)
                #pragma unroll
                for (int j = 0; j < 8; ++j)
                    acc[i][j] = fmaf(av[i], bv[j], acc[i][j]);
        }
    }
    // K tail
    #pragma unroll
    for (int k = 0; k < 2; ++k) {
        float av[8], bv[8];
        #pragma unroll
        for (int i = 0; i < 8; ++i) av[i] = As2[k][ty*8+i];
        #pragma unroll
        for (int j = 0; j < 8; ++j) bv[j] = Bs2[k][tx*8+j];
        #pragma unroll
        for (int i = 0; i < 8; ++i)
            #pragma unroll
            for (int j = 0; j < 8; ++j)
                acc[i][j] = fmaf(av[i], bv[j], acc[i][j]);
    }

    float bias8[8];
    #pragma unroll
    for (int j = 0; j < 8; ++j) bias8[j] = bvec[tx*8+j];

    #pragma unroll
    for (int i = 0; i < 8; ++i) {
        int m = ty*8 + i; int n = base + m;
        float ex = ex_s[m];
        #pragma unroll
        for (int j = 0; j < 8; ++j) acc[i][j] = (acc[i][j] + bias8[j]) * ex;
        if (n < N_NODES) {
            *(float4*)&cf[n*HD + tx*8]     = make_float4(acc[i][0],acc[i][1],acc[i][2],acc[i][3]);
            *(float4*)&cf[n*HD + tx*8 + 4] = make_float4(acc[i][4],acc[i][5],acc[i][6],acc[i][7]);
        }
    }
    #pragma unroll
    for (int j = 0; j < 8; ++j) {
        unsigned mx = 0u;
        #pragma unroll
        for (int i = 0; i < 8; ++i) mx = umax_(mx, fmap(acc[i][j]));
        atomicMax(&colmax[tx*8+j], mx);
    }
    __syncthreads();
    if (t < 128) atomicMax(&ipf0_m[t], colmax[t]);
}

// ---------------------------------------------------------------------------
// geo pass: colmax of (geo @ Wy.T + by) * exists for y in {child_geo, skip}
// (cg/skip only used via their column max -> never materialized)
// ---------------------------------------------------------------------------
__global__ __launch_bounds__(256) void geo_nodes(
    const float* __restrict__ feats,    // [N,128]
    const float* __restrict__ exists,
    const float* __restrict__ W0, const float* __restrict__ b0,
    const float* __restrict__ W1, const float* __restrict__ b1,
    unsigned* __restrict__ acc0, unsigned* __restrict__ acc1)
{
    const float* W  = blockIdx.y ? W1 : W0;
    const float* bv = blockIdx.y ? b1 : b0;
    unsigned* accout = blockIdx.y ? acc1 : acc0;

    __shared__ float As[16][128];
    __shared__ float Bs[16][128];
    __shared__ float ex_s[128];
    __shared__ unsigned colmax[128];
    const int t  = threadIdx.x;
    const int tx = t & 15, ty = t >> 4;
    const int base = blockIdx.x * 128;

    if (t < 128) {
        int n = base + t; if (n >= N_NODES) n = N_NODES - 1;
        ex_s[t] = exists[n];
        colmax[t] = 0u;
    }
    float acc[8][8];
    #pragma unroll
    for (int i = 0; i < 8; ++i)
        #pragma unroll
        for (int j = 0; j < 8; ++j) acc[i][j] = 0.f;

    for (int c = 0; c < 8; ++c) {
        const int kk = c * 16;
        __syncthreads();
        #pragma unroll
        for (int l = 0; l < 2; ++l) {
            int idx = l*256 + t;                    // 0..511
            int m = idx & 127, kq = idx >> 7;       // kq 0..3
            int n = base + m; if (n >= N_NODES) n = N_NODES - 1;
            float4 v = *(const float4*)&feats[n*HD + kk + kq*4];
            As[kq*4+0][m]=v.x; As[kq*4+1][m]=v.y; As[kq*4+2][m]=v.z; As[kq*4+3][m]=v.w;
        }
        #pragma unroll
        for (int l = 0; l < 2; ++l) {
            int idx = l*256 + t;
            int h = idx & 127, kq = idx >> 7;
            float4 v = *(const float4*)&W[h*HD + kk + kq*4];
            Bs[kq*4+0][h]=v.x; Bs[kq*4+1][h]=v.y; Bs[kq*4+2][h]=v.z; Bs[kq*4+3][h]=v.w;
        }
        __syncthreads();
        #pragma unroll
        for (int k = 0; k < 16; ++k) {
            float4 a0 = *(const float4*)&As[k][ty*8];
            float4 a1 = *(const float4*)&As[k][ty*8+4];
            float4 b0 = *(const float4*)&Bs[k][tx*8];
            float4 b1 = *(const float4*)&Bs[k][tx*8+4];
            float av[8] = {a0.x,a0.y,a0.z,a0.w,a1.x,a1.y,a1.z,a1.w};
            float bvv[8] = {b0.x,b0.y,b0.z,b0.w,b1.x,b1.y,b1.z,b1.w};
            #pragma unroll
            for (int i = 0; i < 8; ++i)
                #pragma unroll
                for (int j = 0; j < 8; ++j)
                    acc[i][j] = fmaf(av[i], bvv[j], acc[i][j]);
        }
    }

    float bias8[8];
    #pragma unroll
    for (int j = 0; j < 8; ++j) bias8[j] = bv[tx*8+j];
    #pragma unroll
    for (int j = 0; j < 8; ++j) {
        unsigned mx = 0u;
        #pragma unroll
        for (int i = 0; i < 8; ++i) {
            float v = (acc[i][j] + bias8[j]) * ex_s[ty*8+i];
            mx = umax_(mx, fmap(v));
        }
        atomicMax(&colmax[tx*8+j], mx);
    }
    __syncthreads();
    if (t < 128) atomicMax(&accout[t], colmax[t]);
}

// ---------------------------------------------------------------------------
// edge pass: msg = leaky([cf[from]|cf[to]|ef] @ W.T + b)
//   ipf_out[h] = max(0, max_e msg[e,h])   (int-bits atomicMax, init 0)
//   if DO_SCATTER: cf_dst[from[e]][h] = max over edges (int-bits, init 0)
// ---------------------------------------------------------------------------
template<int DO_SCATTER>
__global__ __launch_bounds__(256) void edge_pass(
    const float* __restrict__ cf_src,   // [N,128]
    const int*   __restrict__ eidx,     // [E,2]
    const float* __restrict__ ef,       // [E,4]
    const float* __restrict__ W,        // [128,260]
    const float* __restrict__ bias,     // [128]
    float* __restrict__ cf_dst,         // [N,128] scatter target (int-bits)
    int*   __restrict__ ipf_out)        // [128]
{
    __shared__ float As[16][128];
    __shared__ float Bs[16][128];
    __shared__ int from_s[128], to_s[128];
    __shared__ float4 efs[128];
    __shared__ float4 wfs[128];
    __shared__ int colmax[128];
    const int t  = threadIdx.x;
    const int tx = t & 15, ty = t >> 4;
    const int base = blockIdx.x * 128;   // 320000/128 = 2500 exact

    if (t < 128) {
        int2 p = *(const int2*)&eidx[(base+t)*2];
        from_s[t] = p.x; to_s[t] = p.y;
        efs[t] = *(const float4*)&ef[(base+t)*4];
        wfs[t] = *(const float4*)&W[t*KE + 256];
        colmax[t] = 0;
    }

    float acc[8][8];
    #pragma unroll
    for (int i = 0; i < 8; ++i)
        #pragma unroll
        for (int j = 0; j < 8; ++j) acc[i][j] = 0.f;

    for (int c = 0; c < 16; ++c) {
        const int koff = (c & 7) * 16;
        __syncthreads();
        #pragma unroll
        for (int l = 0; l < 2; ++l) {               // gather A: 128x16
            int idx = l*256 + t;                    // 0..511
            int m = idx & 127, kq = idx >> 7;
            int node = (c < 8) ? from_s[m] : to_s[m];
            float4 v = *(const float4*)&cf_src[node*HD + koff + kq*4];
            As[kq*4+0][m]=v.x; As[kq*4+1][m]=v.y; As[kq*4+2][m]=v.z; As[kq*4+3][m]=v.w;
        }
        #pragma unroll
        for (int l = 0; l < 2; ++l) {               // B: 16x128
            int idx = l*256 + t;
            int h = idx & 127, kq = idx >> 7;
            float4 v = *(const float4*)&W[h*KE + c*16 + kq*4];
            Bs[kq*4+0][h]=v.x; Bs[kq*4+1][h]=v.y; Bs[kq*4+2][h]=v.z; Bs[kq*4+3][h]=v.w;
        }
        __syncthreads();
        #pragma unroll
        for (int k = 0; k < 16; ++k) {
            float4 a0 = *(const float4*)&As[k][ty*8];
            float4 a1 = *(const float4*)&As[k][ty*8+4];
            float4 b0 = *(const float4*)&Bs[k][tx*8];
            float4 b1 = *(const float4*)&Bs[k][tx*8+4];
            float av[8] = {a0.x,a0.y,a0.z,a0.w,a1.x,a1.y,a1.z,a1.w};
            float bv[8] = {b0.x,b0.y,b0.z,b0.w,b1.x,b1.y,b1.z,b1.w};
            #pragma unroll
            for (int i = 0; i < 8; ++i)
                #pragma unroll
                for (int j = 0; j < 8; ++j)
                    acc[i][j] = fmaf(av[i], bv[j], acc[i][j]);
        }
    }
    // edge-type tail (k = 256..259)
    #pragma unroll
    for (int i = 0; i < 8; ++i) {
        float4 ev = efs[ty*8+i];
        #pragma unroll
        for (int j = 0; j < 8; ++j) {
            float4 wv = wfs[tx*8+j];
            acc[i][j] += ev.x*wv.x + ev.y*wv.y + ev.z*wv.z + ev.w*wv.w;
        }
    }

    float bj[8];
    #pragma unroll
    for (int j = 0; j < 8; ++j) bj[j] = bias[tx*8+j];
    #pragma unroll
    for (int i = 0; i < 8; ++i)
        #pragma unroll
        for (int j = 0; j < 8; ++j)
            acc[i][j] = leaky(acc[i][j] + bj[j]);

    // block column max (int-bits compare; floor 0 is correct: result clamps at 0)
    #pragma unroll
    for (int j = 0; j < 8; ++j) {
        int mx = 0;
        #pragma unroll
        for (int i = 0; i < 8; ++i) {
            int bi = __float_as_int(acc[i][j]);
            mx = mx > bi ? mx : bi;
        }
        atomicMax(&colmax[tx*8+j], mx);
    }
    if (DO_SCATTER) {
        #pragma unroll
        for (int i = 0; i < 8; ++i) {
            int node = from_s[ty*8+i];
            #pragma unroll
            for (int j = 0; j < 8; ++j) {
                if (acc[i][j] > 0.f)
                    atomicMax((int*)&cf_dst[node*HD + tx*8 + j], __float_as_int(acc[i][j]));
            }
        }
    }
    __syncthreads();
    if (t < 128) atomicMax(&ipf_out[t], colmax[t]);
}

// ---------------------------------------------------------------------------
// parent_feat = leaky([ipf0|ipf1|ipf2] @ second_w.T + second_b)
// ---------------------------------------------------------------------------
__global__ __launch_bounds__(128) void head_feat(
    const unsigned* __restrict__ ipf0_m,
    const float* __restrict__ ipf1, const float* __restrict__ ipf2,
    const float* __restrict__ W,    // [128,384]
    const float* __restrict__ bvec, float* __restrict__ out)
{
    __shared__ float s[384];
    const int t = threadIdx.x;
    s[t]       = funmap(ipf0_m[t]);
    s[128 + t] = ipf1[t];
    s[256 + t] = ipf2[t];
    __syncthreads();
    float acc = bvec[t];
    #pragma unroll 4
    for (int k = 0; k < 384; ++k) acc = fmaf(s[k], W[t*384 + k], acc);
    out[t] = leaky(acc);
}

// ---------------------------------------------------------------------------
// parent_geo = leaky(leaky(sg) + GN(leaky(pg) @ sgeo_w.T + sgeo_b) * gnw + gnb)
// ---------------------------------------------------------------------------
__global__ __launch_bounds__(128) void head_geo(
    const unsigned* __restrict__ pg_m, const unsigned* __restrict__ sg_m,
    const float* __restrict__ W,    // [128,128]
    const float* __restrict__ bvec,
    const float* __restrict__ gnw, const float* __restrict__ gnb,
    float* __restrict__ out)
{
    __shared__ float pg[128];
    __shared__ float tt[128];
    const int t = threadIdx.x;
    pg[t] = leaky(funmap(pg_m[t]));
    float sg = leaky(funmap(sg_m[t]));
    __syncthreads();
    float acc = bvec[t];
    #pragma unroll 4
    for (int k = 0; k < 128; ++k) acc = fmaf(pg[k], W[t*128 + k], acc);
    tt[t] = acc;
    __syncthreads();
    const int g = (t >> 3) << 3;   // group base, 16 groups of 8
    float mu = 0.f, m2 = 0.f;
    #pragma unroll
    for (int q = 0; q < 8; ++q) { float x = tt[g + q]; mu += x; m2 += x*x; }
    mu *= 0.125f;
    m2 = m2 * 0.125f - mu * mu;
    float xn = (acc - mu) * rsqrtf(m2 + 1e-5f);
    out[t] = leaky(sg + xn * gnw[t] + gnb[t]);
}

// ---------------------------------------------------------------------------
extern "C" void kernel_launch(void* const* d_in, const int* in_sizes, int n_in,
                              void* d_out, int out_size, void* d_ws, size_t ws_size,
                              hipStream_t stream)
{
    const float* child_feats  = (const float*)d_in[0];
    const float* child_geo    = (const float*)d_in[1];
    const float* child_exists = (const float*)d_in[2];
    const float* etoh         = (const float*)d_in[3];
    const int*   eidx         = (const int*)  d_in[4];
    const float* op_w   = (const float*)d_in[5];
    const float* op_b   = (const float*)d_in[6];
    const float* sec_w  = (const float*)d_in[7];
    const float* sec_b  = (const float*)d_in[8];
    const float* edge_w = (const float*)d_in[9];
    const float* edge_b = (const float*)d_in[10];
    const float* geo_w  = (const float*)d_in[11];
    const float* geo_b  = (const float*)d_in[12];
    const float* sgeo_w = (const float*)d_in[13];
    const float* sgeo_b = (const float*)d_in[14];
    const float* gn_w   = (const float*)d_in[15];
    const float* gn_b   = (const float*)d_in[16];
    const float* skip_w = (const float*)d_in[17];
    const float* skip_b = (const float*)d_in[18];
    float* out = (float*)d_out;

    char* ws = (char*)d_ws;
    float*    cf_a   = (float*)ws;                                   // N*128
    float*    cf_b   = (float*)(ws + (size_t)N_NODES*HD*4);          // N*128
    unsigned* ipf0_m = (unsigned*)(ws + (size_t)2*N_NODES*HD*4);     // 128
    float*    ipf1   = (float*)(ipf0_m + 128);                       // 128
    float*    ipf2   = (float*)(ipf0_m + 256);                       // 128
    unsigned* pg_m   = ipf0_m + 384;                                 // 128
    unsigned* sg_m   = ipf0_m + 512;                                 // 128

    // zero-init scatter target + all max accumulators (0 == mapped minimum
    // for the mapped accums; 0 == correct floor for int-bit >=0 maxes)
    hipMemsetAsync(cf_b, 0, (size_t)N_NODES*HD*4 + 5*128*4, stream);

    encode_nodes<<<(N_NODES + 127)/128, 256, 0, stream>>>(
        child_feats, child_exists, op_w, op_b, cf_a, ipf0_m);

    geo_nodes<<<dim3((N_NODES + 127)/128, 2), 256, 0, stream>>>(
        child_geo, child_exists, geo_w, geo_b, skip_w, skip_b, pg_m, sg_m);

    edge_pass<1><<<N_EDGES/128, 256, 0, stream>>>(
        cf_a, eidx, etoh, edge_w, edge_b, cf_b, (int*)ipf1);

    edge_pass<0><<<N_EDGES/128, 256, 0, stream>>>(
        cf_b, eidx, etoh, edge_w + 128*KE, edge_b + 128, nullptr, (int*)ipf2);

    head_feat<<<1, 128, 0, stream>>>(ipf0_m, ipf1, ipf2, sec_w, sec_b, out);

    head_geo<<<1, 128, 0, stream>>>(pg_m, sg_m, sgeo_w, sgeo_b, gn_w, gn_b, out + 128);
}

// Round 2
// 1080.870 us; speedup vs baseline: 1.2670x; 1.2670x over previous
//
#include <hip/hip_runtime.h>

#define N_NODES 20000
#define N_EDGES 320000
#define HD 128
#define FIN 162      // 24 + 10 + 128
#define KE 260       // 2*H + ETN

typedef unsigned short ushort_t;

__device__ __forceinline__ float leaky(float x){ return x > 0.f ? x : 0.01f*x; }
// monotone float->uint mapping: order-preserving for all finite floats
__device__ __forceinline__ unsigned fmap(float f){
    unsigned u = __float_as_uint(f);
    return (u & 0x80000000u) ? ~u : (u | 0x80000000u);
}
__device__ __forceinline__ float funmap(unsigned u){
    return __uint_as_float((u & 0x80000000u) ? (u & 0x7fffffffu) : ~u);
}
__device__ __forceinline__ unsigned umax_(unsigned a, unsigned b){ return a > b ? a : b; }
// f32 -> bf16 (RTNE) and back
__device__ __forceinline__ ushort_t f2bf(float x){
    unsigned b = __float_as_uint(x);
    return (ushort_t)((b + 0x7fffu + ((b >> 16) & 1u)) >> 16);
}
__device__ __forceinline__ float bf2f(ushort_t u){
    return __uint_as_float(((unsigned)u) << 16);
}

// ---------------------------------------------------------------------------
// cf = (child_feats @ op_w.T + op_b) * exists  ; ipf0_m = mapped colmax(cf)
// ---------------------------------------------------------------------------
__global__ __launch_bounds__(256) void encode_nodes(
    const float* __restrict__ feats,    // [N,162]
    const float* __restrict__ exists,   // [N]
    const float* __restrict__ W,        // [128,162]
    const float* __restrict__ bvec,     // [128]
    float* __restrict__ cf,             // [N,128] out
    unsigned* __restrict__ ipf0_m)      // [128] mapped-uint accum (init 0)
{
    __shared__ float As[16][128];
    __shared__ float Bs[16][128];
    __shared__ float As2[2][128];
    __shared__ float Bs2[2][128];
    __shared__ float ex_s[128];
    __shared__ unsigned colmax[128];
    const int t  = threadIdx.x;
    const int tx = t & 15, ty = t >> 4;
    const int base = blockIdx.x * 128;

    if (t < 128) {
        int n = base + t; if (n >= N_NODES) n = N_NODES - 1;
        ex_s[t] = exists[n];
        colmax[t] = 0u;
        float2 v = *(const float2*)&feats[n*FIN + 160];
        As2[0][t] = v.x; As2[1][t] = v.y;
        float2 w = *(const float2*)&W[t*FIN + 160];
        Bs2[0][t] = w.x; Bs2[1][t] = w.y;
    }

    float acc[8][8];
    #pragma unroll
    for (int i = 0; i < 8; ++i)
        #pragma unroll
        for (int j = 0; j < 8; ++j) acc[i][j] = 0.f;

    for (int c = 0; c < 10; ++c) {
        const int kk = c * 16;
        __syncthreads();
        #pragma unroll
        for (int l = 0; l < 4; ++l) {
            int idx = l*256 + t;
            int m = idx & 127, kh = idx >> 7;
            int n = base + m; if (n >= N_NODES) n = N_NODES - 1;
            float2 v = *(const float2*)&feats[n*FIN + kk + kh*2];
            As[kh*2+0][m] = v.x; As[kh*2+1][m] = v.y;
        }
        #pragma unroll
        for (int l = 0; l < 4; ++l) {
            int idx = l*256 + t;
            int h = idx & 127, kh = idx >> 7;
            float2 v = *(const float2*)&W[h*FIN + kk + kh*2];
            Bs[kh*2+0][h] = v.x; Bs[kh*2+1][h] = v.y;
        }
        __syncthreads();
        #pragma unroll
        for (int k = 0; k < 16; ++k) {
            float4 a0 = *(const float4*)&As[k][ty*8];
            float4 a1 = *(const float4*)&As[k][ty*8+4];
            float4 b0 = *(const float4*)&Bs[k][tx*8];
            float4 b1 = *(const float4*)&Bs[k][tx*8+4];
            float av[8] = {a0.x,a0.y,a0.z,a0.w,a1.x,a1.y,a1.z,a1.w};
            float bv[8] = {b0.x,b0.y,b0.z,b0.w,b1.x,b1.y,b1.z,b1.w};
            #pragma unroll
            for (int i = 0; i < 8; ++i)
                #pragma unroll
                for (int j = 0; j < 8; ++j)
                    acc[i][j] = fmaf(av[i], bv[j], acc[i][j]);
        }
    }
    #pragma unroll
    for (int k = 0; k < 2; ++k) {
        float av[8], bv[8];
        #pragma unroll
        for (int i = 0; i < 8; ++i) av[i] = As2[k][ty*8+i];
        #pragma unroll
        for (int j = 0; j < 8; ++j) bv[j] = Bs2[k][tx*8+j];
        #pragma unroll
        for (int i = 0; i < 8; ++i)
            #pragma unroll
            for (int j = 0; j < 8; ++j)
                acc[i][j] = fmaf(av[i], bv[j], acc[i][j]);
    }

    float bias8[8];
    #pragma unroll
    for (int j = 0; j < 8; ++j) bias8[j] = bvec[tx*8+j];

    #pragma unroll
    for (int i = 0; i < 8; ++i) {
        int m = ty*8 + i; int n = base + m;
        float ex = ex_s[m];
        #pragma unroll
        for (int j = 0; j < 8; ++j) acc[i][j] = (acc[i][j] + bias8[j]) * ex;
        if (n < N_NODES) {
            *(float4*)&cf[n*HD + tx*8]     = make_float4(acc[i][0],acc[i][1],acc[i][2],acc[i][3]);
            *(float4*)&cf[n*HD + tx*8 + 4] = make_float4(acc[i][4],acc[i][5],acc[i][6],acc[i][7]);
        }
    }
    #pragma unroll
    for (int j = 0; j < 8; ++j) {
        unsigned mx = 0u;
        #pragma unroll
        for (int i = 0; i < 8; ++i) mx = umax_(mx, fmap(acc[i][j]));
        atomicMax(&colmax[tx*8+j], mx);
    }
    __syncthreads();
    if (t < 128) atomicMax(&ipf0_m[t], colmax[t]);
}

// ---------------------------------------------------------------------------
// geo pass: colmax of (geo @ Wy.T + by) * exists for y in {child_geo, skip}
// ---------------------------------------------------------------------------
__global__ __launch_bounds__(256) void geo_nodes(
    const float* __restrict__ feats,    // [N,128]
    const float* __restrict__ exists,
    const float* __restrict__ W0, const float* __restrict__ b0,
    const float* __restrict__ W1, const float* __restrict__ b1,
    unsigned* __restrict__ acc0, unsigned* __restrict__ acc1)
{
    const float* W  = blockIdx.y ? W1 : W0;
    const float* bv = blockIdx.y ? b1 : b0;
    unsigned* accout = blockIdx.y ? acc1 : acc0;

    __shared__ float As[16][128];
    __shared__ float Bs[16][128];
    __shared__ float ex_s[128];
    __shared__ unsigned colmax[128];
    const int t  = threadIdx.x;
    const int tx = t & 15, ty = t >> 4;
    const int base = blockIdx.x * 128;

    if (t < 128) {
        int n = base + t; if (n >= N_NODES) n = N_NODES - 1;
        ex_s[t] = exists[n];
        colmax[t] = 0u;
    }
    float acc[8][8];
    #pragma unroll
    for (int i = 0; i < 8; ++i)
        #pragma unroll
        for (int j = 0; j < 8; ++j) acc[i][j] = 0.f;

    for (int c = 0; c < 8; ++c) {
        const int kk = c * 16;
        __syncthreads();
        #pragma unroll
        for (int l = 0; l < 2; ++l) {
            int idx = l*256 + t;
            int m = idx & 127, kq = idx >> 7;
            int n = base + m; if (n >= N_NODES) n = N_NODES - 1;
            float4 v = *(const float4*)&feats[n*HD + kk + kq*4];
            As[kq*4+0][m]=v.x; As[kq*4+1][m]=v.y; As[kq*4+2][m]=v.z; As[kq*4+3][m]=v.w;
        }
        #pragma unroll
        for (int l = 0; l < 2; ++l) {
            int idx = l*256 + t;
            int h = idx & 127, kq = idx >> 7;
            float4 v = *(const float4*)&W[h*HD + kk + kq*4];
            Bs[kq*4+0][h]=v.x; Bs[kq*4+1][h]=v.y; Bs[kq*4+2][h]=v.z; Bs[kq*4+3][h]=v.w;
        }
        __syncthreads();
        #pragma unroll
        for (int k = 0; k < 16; ++k) {
            float4 a0 = *(const float4*)&As[k][ty*8];
            float4 a1 = *(const float4*)&As[k][ty*8+4];
            float4 b0 = *(const float4*)&Bs[k][tx*8];
            float4 b1 = *(const float4*)&Bs[k][tx*8+4];
            float av[8] = {a0.x,a0.y,a0.z,a0.w,a1.x,a1.y,a1.z,a1.w};
            float bvv[8] = {b0.x,b0.y,b0.z,b0.w,b1.x,b1.y,b1.z,b1.w};
            #pragma unroll
            for (int i = 0; i < 8; ++i)
                #pragma unroll
                for (int j = 0; j < 8; ++j)
                    acc[i][j] = fmaf(av[i], bvv[j], acc[i][j]);
        }
    }

    float bias8[8];
    #pragma unroll
    for (int j = 0; j < 8; ++j) bias8[j] = bv[tx*8+j];
    #pragma unroll
    for (int j = 0; j < 8; ++j) {
        unsigned mx = 0u;
        #pragma unroll
        for (int i = 0; i < 8; ++i) {
            float v = (acc[i][j] + bias8[j]) * ex_s[ty*8+i];
            mx = umax_(mx, fmap(v));
        }
        atomicMax(&colmax[tx*8+j], mx);
    }
    __syncthreads();
    if (t < 128) atomicMax(&accout[t], colmax[t]);
}

// ---------------------------------------------------------------------------
// edge pass: msg = leaky([cf[from]|cf[to]|ef] @ W.T + b)
//   ipf_out[h] = max(0, max_e msg[e,h])   (int-bits atomicMax, init 0)
//   if STORE_MSG: msgb[e][h] = bf16(msg)  (dense coalesced stores — no atomics)
// ---------------------------------------------------------------------------
template<int STORE_MSG>
__global__ __launch_bounds__(256) void edge_pass(
    const float* __restrict__ cf_src,   // [N,128]
    const int*   __restrict__ eidx,     // [E,2]
    const float* __restrict__ ef,       // [E,4]
    const float* __restrict__ W,        // [128,260]
    const float* __restrict__ bias,     // [128]
    ushort_t* __restrict__ msgb,        // [E,128] bf16 messages
    int*   __restrict__ ipf_out)        // [128]
{
    __shared__ float As[16][128];
    __shared__ float Bs[16][128];
    __shared__ int from_s[128], to_s[128];
    __shared__ float4 efs[128];
    __shared__ float4 wfs[128];
    __shared__ int colmax[128];
    const int t  = threadIdx.x;
    const int tx = t & 15, ty = t >> 4;
    const int base = blockIdx.x * 128;   // 320000/128 = 2500 exact

    if (t < 128) {
        int2 p = *(const int2*)&eidx[(base+t)*2];
        from_s[t] = p.x; to_s[t] = p.y;
        efs[t] = *(const float4*)&ef[(base+t)*4];
        wfs[t] = *(const float4*)&W[t*KE + 256];
        colmax[t] = 0;
    }

    float acc[8][8];
    #pragma unroll
    for (int i = 0; i < 8; ++i)
        #pragma unroll
        for (int j = 0; j < 8; ++j) acc[i][j] = 0.f;

    for (int c = 0; c < 16; ++c) {
        const int koff = (c & 7) * 16;
        __syncthreads();
        #pragma unroll
        for (int l = 0; l < 2; ++l) {               // gather A: 128x16
            int idx = l*256 + t;
            int m = idx & 127, kq = idx >> 7;
            int node = (c < 8) ? from_s[m] : to_s[m];
            float4 v = *(const float4*)&cf_src[node*HD + koff + kq*4];
            As[kq*4+0][m]=v.x; As[kq*4+1][m]=v.y; As[kq*4+2][m]=v.z; As[kq*4+3][m]=v.w;
        }
        #pragma unroll
        for (int l = 0; l < 2; ++l) {               // B: 16x128
            int idx = l*256 + t;
            int h = idx & 127, kq = idx >> 7;
            float4 v = *(const float4*)&W[h*KE + c*16 + kq*4];
            Bs[kq*4+0][h]=v.x; Bs[kq*4+1][h]=v.y; Bs[kq*4+2][h]=v.z; Bs[kq*4+3][h]=v.w;
        }
        __syncthreads();
        #pragma unroll
        for (int k = 0; k < 16; ++k) {
            float4 a0 = *(const float4*)&As[k][ty*8];
            float4 a1 = *(const float4*)&As[k][ty*8+4];
            float4 b0 = *(const float4*)&Bs[k][tx*8];
            float4 b1 = *(const float4*)&Bs[k][tx*8+4];
            float av[8] = {a0.x,a0.y,a0.z,a0.w,a1.x,a1.y,a1.z,a1.w};
            float bv[8] = {b0.x,b0.y,b0.z,b0.w,b1.x,b1.y,b1.z,b1.w};
            #pragma unroll
            for (int i = 0; i < 8; ++i)
                #pragma unroll
                for (int j = 0; j < 8; ++j)
                    acc[i][j] = fmaf(av[i], bv[j], acc[i][j]);
        }
    }
    // edge-type tail (k = 256..259)
    #pragma unroll
    for (int i = 0; i < 8; ++i) {
        float4 ev = efs[ty*8+i];
        #pragma unroll
        for (int j = 0; j < 8; ++j) {
            float4 wv = wfs[tx*8+j];
            acc[i][j] += ev.x*wv.x + ev.y*wv.y + ev.z*wv.z + ev.w*wv.w;
        }
    }

    float bj[8];
    #pragma unroll
    for (int j = 0; j < 8; ++j) bj[j] = bias[tx*8+j];
    #pragma unroll
    for (int i = 0; i < 8; ++i)
        #pragma unroll
        for (int j = 0; j < 8; ++j)
            acc[i][j] = leaky(acc[i][j] + bj[j]);

    // block column max (int-bits compare; floor 0 correct: result clamps at 0)
    #pragma unroll
    for (int j = 0; j < 8; ++j) {
        int mx = 0;
        #pragma unroll
        for (int i = 0; i < 8; ++i) {
            int bi = __float_as_int(acc[i][j]);
            mx = mx > bi ? mx : bi;
        }
        atomicMax(&colmax[tx*8+j], mx);
    }
    if (STORE_MSG) {
        #pragma unroll
        for (int i = 0; i < 8; ++i) {
            int e = base + ty*8 + i;
            union { ushort_t us[8]; uint4 v; } pk;
            #pragma unroll
            for (int j = 0; j < 8; ++j) pk.us[j] = f2bf(acc[i][j]);
            *(uint4*)&msgb[(size_t)e*HD + tx*8] = pk.v;
        }
    }
    __syncthreads();
    if (t < 128) atomicMax(&ipf_out[t], colmax[t]);
}

// ---------------------------------------------------------------------------
// CSR build: histogram -> scan -> fill
// ---------------------------------------------------------------------------
__global__ __launch_bounds__(256) void hist_from(
    const int* __restrict__ eidx, int* __restrict__ count)
{
    int e = blockIdx.x * 256 + threadIdx.x;   // grid sized exactly E
    atomicAdd(&count[eidx[2*e]], 1);
}

__global__ __launch_bounds__(256) void scan_offsets(
    const int* __restrict__ count, int* __restrict__ offset)
{
    __shared__ int part[256];
    const int t = threadIdx.x;
    const int lo = t * 79;
    const int hi = min(lo + 79, N_NODES);
    int s = 0;
    for (int n = lo; n < hi; ++n) s += count[n];
    part[t] = s;
    __syncthreads();
    for (int d = 1; d < 256; d <<= 1) {
        int v = (t >= d) ? part[t - d] : 0;
        __syncthreads();
        part[t] += v;
        __syncthreads();
    }
    int run = (t > 0) ? part[t - 1] : 0;
    for (int n = lo; n < hi; ++n) { offset[n] = run; run += count[n]; }
}

__global__ __launch_bounds__(256) void fill_elist(
    const int* __restrict__ eidx, const int* __restrict__ offset,
    int* __restrict__ cursor, int* __restrict__ elist)
{
    int e = blockIdx.x * 256 + threadIdx.x;
    int f = eidx[2*e];
    int p = atomicAdd(&cursor[f], 1);
    elist[offset[f] + p] = e;
}

// ---------------------------------------------------------------------------
// segment max: cf_b[n][ch] = max(0, max_{e: from[e]=n} msg[e][ch])
// one block (128 threads) per node; each thread owns one channel
// ---------------------------------------------------------------------------
__global__ __launch_bounds__(128) void segmax(
    const ushort_t* __restrict__ msgb,  // [E,128] bf16
    const int* __restrict__ offset, const int* __restrict__ count,
    const int* __restrict__ elist,
    float* __restrict__ cf_b)           // [N,128]
{
    __shared__ int es[128];
    const int n = blockIdx.x;
    const int t = threadIdx.x;
    const int off = offset[n];
    const int deg = count[n];
    float m = 0.f;
    for (int s0 = 0; s0 < deg; s0 += 128) {
        int nd = min(128, deg - s0);
        __syncthreads();
        if (t < nd) es[t] = elist[off + s0 + t];
        __syncthreads();
        for (int d = 0; d < nd; ++d) {
            ushort_t u = msgb[(size_t)es[d]*HD + t];
            m = fmaxf(m, bf2f(u));
        }
    }
    cf_b[(size_t)n*HD + t] = m;
}

// ---------------------------------------------------------------------------
// parent_feat = leaky([ipf0|ipf1|ipf2] @ second_w.T + second_b)
// ---------------------------------------------------------------------------
__global__ __launch_bounds__(128) void head_feat(
    const unsigned* __restrict__ ipf0_m,
    const float* __restrict__ ipf1, const float* __restrict__ ipf2,
    const float* __restrict__ W,    // [128,384]
    const float* __restrict__ bvec, float* __restrict__ out)
{
    __shared__ float s[384];
    const int t = threadIdx.x;
    s[t]       = funmap(ipf0_m[t]);
    s[128 + t] = ipf1[t];
    s[256 + t] = ipf2[t];
    __syncthreads();
    float acc = bvec[t];
    #pragma unroll 4
    for (int k = 0; k < 384; ++k) acc = fmaf(s[k], W[t*384 + k], acc);
    out[t] = leaky(acc);
}

// ---------------------------------------------------------------------------
// parent_geo = leaky(leaky(sg) + GN(leaky(pg) @ sgeo_w.T + sgeo_b) * gnw + gnb)
// ---------------------------------------------------------------------------
__global__ __launch_bounds__(128) void head_geo(
    const unsigned* __restrict__ pg_m, const unsigned* __restrict__ sg_m,
    const float* __restrict__ W,    // [128,128]
    const float* __restrict__ bvec,
    const float* __restrict__ gnw, const float* __restrict__ gnb,
    float* __restrict__ out)
{
    __shared__ float pg[128];
    __shared__ float tt[128];
    const int t = threadIdx.x;
    pg[t] = leaky(funmap(pg_m[t]));
    float sg = leaky(funmap(sg_m[t]));
    __syncthreads();
    float acc = bvec[t];
    #pragma unroll 4
    for (int k = 0; k < 128; ++k) acc = fmaf(pg[k], W[t*128 + k], acc);
    tt[t] = acc;
    __syncthreads();
    const int g = (t >> 3) << 3;   // group base, 16 groups of 8
    float mu = 0.f, m2 = 0.f;
    #pragma unroll
    for (int q = 0; q < 8; ++q) { float x = tt[g + q]; mu += x; m2 += x*x; }
    mu *= 0.125f;
    m2 = m2 * 0.125f - mu * mu;
    float xn = (acc - mu) * rsqrtf(m2 + 1e-5f);
    out[t] = leaky(sg + xn * gnw[t] + gnb[t]);
}

// ---------------------------------------------------------------------------
extern "C" void kernel_launch(void* const* d_in, const int* in_sizes, int n_in,
                              void* d_out, int out_size, void* d_ws, size_t ws_size,
                              hipStream_t stream)
{
    const float* child_feats  = (const float*)d_in[0];
    const float* child_geo    = (const float*)d_in[1];
    const float* child_exists = (const float*)d_in[2];
    const float* etoh         = (const float*)d_in[3];
    const int*   eidx         = (const int*)  d_in[4];
    const float* op_w   = (const float*)d_in[5];
    const float* op_b   = (const float*)d_in[6];
    const float* sec_w  = (const float*)d_in[7];
    const float* sec_b  = (const float*)d_in[8];
    const float* edge_w = (const float*)d_in[9];
    const float* edge_b = (const float*)d_in[10];
    const float* geo_w  = (const float*)d_in[11];
    const float* geo_b  = (const float*)d_in[12];
    const float* sgeo_w = (const float*)d_in[13];
    const float* sgeo_b = (const float*)d_in[14];
    const float* gn_w   = (const float*)d_in[15];
    const float* gn_b   = (const float*)d_in[16];
    const float* skip_w = (const float*)d_in[17];
    const float* skip_b = (const float*)d_in[18];
    float* out = (float*)d_out;

    // workspace layout (all 16B aligned)
    char* ws = (char*)d_ws;
    size_t off = 0;
    float*    cf_a   = (float*)(ws + off);  off += (size_t)N_NODES*HD*4;      // 10.24 MB
    float*    cf_b   = (float*)(ws + off);  off += (size_t)N_NODES*HD*4;      // 10.24 MB
    ushort_t* msgb   = (ushort_t*)(ws + off); off += (size_t)N_EDGES*HD*2;    // 81.92 MB
    int*      elist  = (int*)(ws + off);    off += (size_t)N_EDGES*4;         // 1.28 MB
    int*      offs   = (int*)(ws + off);    off += (size_t)N_NODES*4;         // 80 KB
    // zero-region: accums (5*128 u32) + count + cursor
    char*     zero0  = ws + off;
    unsigned* ipf0_m = (unsigned*)(ws + off); off += 128*4;
    float*    ipf1   = (float*)(ws + off);    off += 128*4;
    float*    ipf2   = (float*)(ws + off);    off += 128*4;
    unsigned* pg_m   = (unsigned*)(ws + off); off += 128*4;
    unsigned* sg_m   = (unsigned*)(ws + off); off += 128*4;
    int*      count  = (int*)(ws + off);      off += (size_t)N_NODES*4;
    int*      cursor = (int*)(ws + off);      off += (size_t)N_NODES*4;
    size_t zero_bytes = (size_t)(ws + off - zero0);

    hipMemsetAsync(zero0, 0, zero_bytes, stream);

    // CSR build (independent of GEMMs)
    hist_from<<<N_EDGES/256, 256, 0, stream>>>(eidx, count);
    scan_offsets<<<1, 256, 0, stream>>>(count, offs);
    fill_elist<<<N_EDGES/256, 256, 0, stream>>>(eidx, offs, cursor, elist);

    encode_nodes<<<(N_NODES + 127)/128, 256, 0, stream>>>(
        child_feats, child_exists, op_w, op_b, cf_a, ipf0_m);

    geo_nodes<<<dim3((N_NODES + 127)/128, 2), 256, 0, stream>>>(
        child_geo, child_exists, geo_w, geo_b, skip_w, skip_b, pg_m, sg_m);

    // iter 1: messages -> dense bf16 + column max
    edge_pass<1><<<N_EDGES/128, 256, 0, stream>>>(
        cf_a, eidx, etoh, edge_w, edge_b, msgb, (int*)ipf1);

    // segment max -> cf_b
    segmax<<<N_NODES, 128, 0, stream>>>(msgb, offs, count, elist, cf_b);

    // iter 2: only column max needed
    edge_pass<0><<<N_EDGES/128, 256, 0, stream>>>(
        cf_b, eidx, etoh, edge_w + 128*KE, edge_b + 128, nullptr, (int*)ipf2);

    head_feat<<<1, 128, 0, stream>>>(ipf0_m, ipf1, ipf2, sec_w, sec_b, out);

    head_geo<<<1, 128, 0, stream>>>(pg_m, sg_m, sgeo_w, sgeo_b, gn_w, gn_b, out + 128);
}

// Round 3
// 542.883 us; speedup vs baseline: 2.5226x; 1.9910x over previous
//
#include <hip/hip_runtime.h>

#define N_NODES 20000
#define N_EDGES 320000
#define HD 128
#define FIN 162      // 24 + 10 + 128
#define KE 260       // 2*H + ETN
#define KPAD 288     // 9 chunks of 32 (256..259 = edge-type, rest zero)
#define ASTR 40      // LDS row stride (bf16 units): 80 B -> 16B aligned, <=2-way bank alias

typedef unsigned short u16;
typedef __attribute__((ext_vector_type(8))) short bf16x8;
typedef __attribute__((ext_vector_type(4))) float f32x4;

__device__ __forceinline__ float leaky(float x){ return x > 0.f ? x : 0.01f*x; }
__device__ __forceinline__ unsigned fmap(float f){
    unsigned u = __float_as_uint(f);
    return (u & 0x80000000u) ? ~u : (u | 0x80000000u);
}
__device__ __forceinline__ float funmap(unsigned u){
    return __uint_as_float((u & 0x80000000u) ? (u & 0x7fffffffu) : ~u);
}
__device__ __forceinline__ unsigned umax_(unsigned a, unsigned b){ return a > b ? a : b; }
__device__ __forceinline__ u16 f2bf(float x){
    unsigned b = __float_as_uint(x);
    return (u16)((b + 0x7fffu + ((b >> 16) & 1u)) >> 16);
}
__device__ __forceinline__ float bf2f(u16 u){
    return __uint_as_float(((unsigned)u) << 16);
}

// ---------------------------------------------------------------------------
// cf = bf16((child_feats @ op_w.T + op_b) * exists) ; ipf0_m = mapped colmax
// ---------------------------------------------------------------------------
__global__ __launch_bounds__(256) void encode_nodes(
    const float* __restrict__ feats,    // [N,162]
    const float* __restrict__ exists,   // [N]
    const float* __restrict__ W,        // [128,162]
    const float* __restrict__ bvec,     // [128]
    u16* __restrict__ cf,               // [N,128] bf16 out
    unsigned* __restrict__ ipf0_m)      // [128] mapped-uint accum (init 0)
{
    __shared__ float As[16][128];
    __shared__ float Bs[16][128];
    __shared__ float As2[2][128];
    __shared__ float Bs2[2][128];
    __shared__ float ex_s[128];
    __shared__ unsigned colmax[128];
    const int t  = threadIdx.x;
    const int tx = t & 15, ty = t >> 4;
    const int base = blockIdx.x * 128;

    if (t < 128) {
        int n = base + t; if (n >= N_NODES) n = N_NODES - 1;
        ex_s[t] = exists[n];
        colmax[t] = 0u;
        float2 v = *(const float2*)&feats[n*FIN + 160];
        As2[0][t] = v.x; As2[1][t] = v.y;
        float2 w = *(const float2*)&W[t*FIN + 160];
        Bs2[0][t] = w.x; Bs2[1][t] = w.y;
    }

    float acc[8][8];
    #pragma unroll
    for (int i = 0; i < 8; ++i)
        #pragma unroll
        for (int j = 0; j < 8; ++j) acc[i][j] = 0.f;

    for (int c = 0; c < 10; ++c) {
        const int kk = c * 16;
        __syncthreads();
        #pragma unroll
        for (int l = 0; l < 4; ++l) {
            int idx = l*256 + t;
            int m = idx & 127, kh = idx >> 7;
            int n = base + m; if (n >= N_NODES) n = N_NODES - 1;
            float2 v = *(const float2*)&feats[n*FIN + kk + kh*2];
            As[kh*2+0][m] = v.x; As[kh*2+1][m] = v.y;
        }
        #pragma unroll
        for (int l = 0; l < 4; ++l) {
            int idx = l*256 + t;
            int h = idx & 127, kh = idx >> 7;
            float2 v = *(const float2*)&W[h*FIN + kk + kh*2];
            Bs[kh*2+0][h] = v.x; Bs[kh*2+1][h] = v.y;
        }
        __syncthreads();
        #pragma unroll
        for (int k = 0; k < 16; ++k) {
            float4 a0 = *(const float4*)&As[k][ty*8];
            float4 a1 = *(const float4*)&As[k][ty*8+4];
            float4 b0 = *(const float4*)&Bs[k][tx*8];
            float4 b1 = *(const float4*)&Bs[k][tx*8+4];
            float av[8] = {a0.x,a0.y,a0.z,a0.w,a1.x,a1.y,a1.z,a1.w};
            float bv[8] = {b0.x,b0.y,b0.z,b0.w,b1.x,b1.y,b1.z,b1.w};
            #pragma unroll
            for (int i = 0; i < 8; ++i)
                #pragma unroll
                for (int j = 0; j < 8; ++j)
                    acc[i][j] = fmaf(av[i], bv[j], acc[i][j]);
        }
    }
    #pragma unroll
    for (int k = 0; k < 2; ++k) {
        float av[8], bv[8];
        #pragma unroll
        for (int i = 0; i < 8; ++i) av[i] = As2[k][ty*8+i];
        #pragma unroll
        for (int j = 0; j < 8; ++j) bv[j] = Bs2[k][tx*8+j];
        #pragma unroll
        for (int i = 0; i < 8; ++i)
            #pragma unroll
            for (int j = 0; j < 8; ++j)
                acc[i][j] = fmaf(av[i], bv[j], acc[i][j]);
    }

    float bias8[8];
    #pragma unroll
    for (int j = 0; j < 8; ++j) bias8[j] = bvec[tx*8+j];

    #pragma unroll
    for (int i = 0; i < 8; ++i) {
        int m = ty*8 + i; int n = base + m;
        float ex = ex_s[m];
        #pragma unroll
        for (int j = 0; j < 8; ++j) acc[i][j] = (acc[i][j] + bias8[j]) * ex;
        if (n < N_NODES) {
            union { u16 us[8]; uint4 v; } pk;
            #pragma unroll
            for (int j = 0; j < 8; ++j) pk.us[j] = f2bf(acc[i][j]);
            *(uint4*)&cf[n*HD + tx*8] = pk.v;
        }
    }
    #pragma unroll
    for (int j = 0; j < 8; ++j) {
        unsigned mx = 0u;
        #pragma unroll
        for (int i = 0; i < 8; ++i) mx = umax_(mx, fmap(acc[i][j]));
        atomicMax(&colmax[tx*8+j], mx);
    }
    __syncthreads();
    if (t < 128) atomicMax(&ipf0_m[t], colmax[t]);
}

// ---------------------------------------------------------------------------
// geo pass: colmax of (geo @ Wy.T + by) * exists for y in {child_geo, skip}
// ---------------------------------------------------------------------------
__global__ __launch_bounds__(256) void geo_nodes(
    const float* __restrict__ feats,    // [N,128]
    const float* __restrict__ exists,
    const float* __restrict__ W0, const float* __restrict__ b0,
    const float* __restrict__ W1, const float* __restrict__ b1,
    unsigned* __restrict__ acc0, unsigned* __restrict__ acc1)
{
    const float* W  = blockIdx.y ? W1 : W0;
    const float* bv = blockIdx.y ? b1 : b0;
    unsigned* accout = blockIdx.y ? acc1 : acc0;

    __shared__ float As[16][128];
    __shared__ float Bs[16][128];
    __shared__ float ex_s[128];
    __shared__ unsigned colmax[128];
    const int t  = threadIdx.x;
    const int tx = t & 15, ty = t >> 4;
    const int base = blockIdx.x * 128;

    if (t < 128) {
        int n = base + t; if (n >= N_NODES) n = N_NODES - 1;
        ex_s[t] = exists[n];
        colmax[t] = 0u;
    }
    float acc[8][8];
    #pragma unroll
    for (int i = 0; i < 8; ++i)
        #pragma unroll
        for (int j = 0; j < 8; ++j) acc[i][j] = 0.f;

    for (int c = 0; c < 8; ++c) {
        const int kk = c * 16;
        __syncthreads();
        #pragma unroll
        for (int l = 0; l < 2; ++l) {
            int idx = l*256 + t;
            int m = idx & 127, kq = idx >> 7;
            int n = base + m; if (n >= N_NODES) n = N_NODES - 1;
            float4 v = *(const float4*)&feats[n*HD + kk + kq*4];
            As[kq*4+0][m]=v.x; As[kq*4+1][m]=v.y; As[kq*4+2][m]=v.z; As[kq*4+3][m]=v.w;
        }
        #pragma unroll
        for (int l = 0; l < 2; ++l) {
            int idx = l*256 + t;
            int h = idx & 127, kq = idx >> 7;
            float4 v = *(const float4*)&W[h*HD + kk + kq*4];
            Bs[kq*4+0][h]=v.x; Bs[kq*4+1][h]=v.y; Bs[kq*4+2][h]=v.z; Bs[kq*4+3][h]=v.w;
        }
        __syncthreads();
        #pragma unroll
        for (int k = 0; k < 16; ++k) {
            float4 a0 = *(const float4*)&As[k][ty*8];
            float4 a1 = *(const float4*)&As[k][ty*8+4];
            float4 b0 = *(const float4*)&Bs[k][tx*8];
            float4 b1 = *(const float4*)&Bs[k][tx*8+4];
            float av[8] = {a0.x,a0.y,a0.z,a0.w,a1.x,a1.y,a1.z,a1.w};
            float bvv[8] = {b0.x,b0.y,b0.z,b0.w,b1.x,b1.y,b1.z,b1.w};
            #pragma unroll
            for (int i = 0; i < 8; ++i)
                #pragma unroll
                for (int j = 0; j < 8; ++j)
                    acc[i][j] = fmaf(av[i], bvv[j], acc[i][j]);
        }
    }

    float bias8[8];
    #pragma unroll
    for (int j = 0; j < 8; ++j) bias8[j] = bv[tx*8+j];
    #pragma unroll
    for (int j = 0; j < 8; ++j) {
        unsigned mx = 0u;
        #pragma unroll
        for (int i = 0; i < 8; ++i) {
            float v = (acc[i][j] + bias8[j]) * ex_s[ty*8+i];
            mx = umax_(mx, fmap(v));
        }
        atomicMax(&colmax[tx*8+j], mx);
    }
    __syncthreads();
    if (t < 128) atomicMax(&accout[t], colmax[t]);
}

// ---------------------------------------------------------------------------
// weight convert: Wb[layer][128][288] bf16, cols 260..287 zero
// ---------------------------------------------------------------------------
__global__ __launch_bounds__(256) void conv_w(
    const float* __restrict__ w, u16* __restrict__ Wb)
{
    const int layer = blockIdx.x;
    const float* src = w + (size_t)layer * 128 * KE;
    u16* dst = Wb + (size_t)layer * 128 * KPAD;
    for (int i = threadIdx.x; i < 128 * KPAD; i += 256) {
        int h = i / KPAD, k = i - h * KPAD;
        dst[i] = (k < KE) ? f2bf(src[h * KE + k]) : (u16)0;
    }
}

// ---------------------------------------------------------------------------
// MFMA edge pass: msg = leaky([cf[from]|cf[to]|ef] @ W.T + b)  (bf16 MFMA)
//   ipf_out[h] = max(0, max_e msg[e,h])
//   STORE_MSG: msgb[e][h] = bf16(msg)
// 128 edges x 128 ch per block; 4 waves in 2x2 grid (64x64 each); K = 9x32
// ---------------------------------------------------------------------------
template<int STORE_MSG>
__global__ __launch_bounds__(256) void edge_mfma(
    const u16* __restrict__ cfb,     // [N,128] bf16
    const int* __restrict__ eidx,    // [E,2]
    const float* __restrict__ ef,    // [E,4]
    const u16* __restrict__ Wb,      // [128,288] bf16 (padded)
    const float* __restrict__ bias,  // [128]
    u16* __restrict__ msgb,          // [E,128] bf16
    int* __restrict__ ipf_out)       // [128]
{
    __shared__ __align__(16) u16 As[2][128 * ASTR];
    __shared__ __align__(16) u16 Bs[2][128 * ASTR];
    __shared__ int from_s[128], to_s[128];
    __shared__ int colmax_s[128];

    const int t    = threadIdx.x;
    const int base = blockIdx.x * 128;        // 2500 blocks exact
    const int wave = t >> 6, l = t & 63;
    const int quad = l >> 4, lc = l & 15;
    const int R0 = (wave >> 1) * 64;          // edge-row base for this wave
    const int C0 = (wave & 1) * 64;           // channel base for this wave
    const int row = t & 127;
    const bool isA = (t < 128);               // waves 0,1 stage A; 2,3 stage B

    if (t < 128) {
        int2 p = ((const int2*)eidx)[base + t];
        from_s[t] = p.x; to_s[t] = p.y;
        colmax_s[t] = 0;
    }
    __syncthreads();

    uint4 pref[4];
    auto prefetch = [&](int c) {
        if (isA) {
            if (c < 8) {
                int node = (c < 4) ? from_s[row] : to_s[row];
                const uint4* src = (const uint4*)(cfb + node * HD + (c & 3) * 32);
                pref[0] = src[0]; pref[1] = src[1]; pref[2] = src[2]; pref[3] = src[3];
            } else {
                float4 e4 = ((const float4*)ef)[base + row];
                unsigned lo = ((unsigned)f2bf(e4.x)) | ((unsigned)f2bf(e4.y) << 16);
                unsigned hi = ((unsigned)f2bf(e4.z)) | ((unsigned)f2bf(e4.w) << 16);
                pref[0] = make_uint4(lo, hi, 0u, 0u);
                pref[1] = make_uint4(0,0,0,0);
                pref[2] = make_uint4(0,0,0,0);
                pref[3] = make_uint4(0,0,0,0);
            }
        } else {
            const uint4* src = (const uint4*)(Wb + row * KPAD + c * 32);
            pref[0] = src[0]; pref[1] = src[1]; pref[2] = src[2]; pref[3] = src[3];
        }
    };
    auto commit = [&](int c) {
        u16* dst = (isA ? As[c & 1] : Bs[c & 1]) + row * ASTR;
        *(uint4*)(dst +  0) = pref[0];
        *(uint4*)(dst +  8) = pref[1];
        *(uint4*)(dst + 16) = pref[2];
        *(uint4*)(dst + 24) = pref[3];
    };

    prefetch(0); commit(0);
    __syncthreads();

    f32x4 acc[4][4];
    #pragma unroll
    for (int i = 0; i < 4; ++i)
        #pragma unroll
        for (int j = 0; j < 4; ++j) acc[i][j] = (f32x4){0.f, 0.f, 0.f, 0.f};

    for (int c = 0; c < 9; ++c) {
        if (c < 8) prefetch(c + 1);
        const u16* Ab = As[c & 1] + (R0 + lc) * ASTR + quad * 8;
        const u16* Bb = Bs[c & 1] + (C0 + lc) * ASTR + quad * 8;
        bf16x8 af[4], bfr[4];
        #pragma unroll
        for (int ti = 0; ti < 4; ++ti) af[ti]  = *(const bf16x8*)(Ab + ti * 16 * ASTR);
        #pragma unroll
        for (int tj = 0; tj < 4; ++tj) bfr[tj] = *(const bf16x8*)(Bb + tj * 16 * ASTR);
        #pragma unroll
        for (int ti = 0; ti < 4; ++ti)
            #pragma unroll
            for (int tj = 0; tj < 4; ++tj)
                acc[ti][tj] = __builtin_amdgcn_mfma_f32_16x16x32_bf16(
                    af[ti], bfr[tj], acc[ti][tj], 0, 0, 0);
        if (c < 8) { commit(c + 1); __syncthreads(); }
    }

    // epilogue: bias + leaky, column max, optional bf16 message store
    #pragma unroll
    for (int tj = 0; tj < 4; ++tj) {
        const int col = C0 + tj * 16 + lc;
        const float bc = bias[col];
        float mx = 0.f;
        #pragma unroll
        for (int ti = 0; ti < 4; ++ti) {
            f32x4 v = acc[ti][tj];
            #pragma unroll
            for (int r = 0; r < 4; ++r) {
                float x = leaky(v[r] + bc);
                if (STORE_MSG)
                    msgb[(size_t)(base + R0 + ti * 16 + quad * 4 + r) * HD + col] = f2bf(x);
                mx = fmaxf(mx, x);
            }
        }
        atomicMax(&colmax_s[col], __float_as_int(mx));   // mx >= 0: int-bits OK
    }
    __syncthreads();
    if (t < 128) atomicMax(&ipf_out[t], colmax_s[t]);
}

// ---------------------------------------------------------------------------
// CSR build: histogram -> scan -> fill
// ---------------------------------------------------------------------------
__global__ __launch_bounds__(256) void hist_from(
    const int* __restrict__ eidx, int* __restrict__ count)
{
    int e = blockIdx.x * 256 + threadIdx.x;
    atomicAdd(&count[eidx[2*e]], 1);
}

__global__ __launch_bounds__(256) void scan_offsets(
    const int* __restrict__ count, int* __restrict__ offset)
{
    __shared__ int part[256];
    const int t = threadIdx.x;
    const int lo = t * 79;
    const int hi = min(lo + 79, N_NODES);
    int s = 0;
    for (int n = lo; n < hi; ++n) s += count[n];
    part[t] = s;
    __syncthreads();
    for (int d = 1; d < 256; d <<= 1) {
        int v = (t >= d) ? part[t - d] : 0;
        __syncthreads();
        part[t] += v;
        __syncthreads();
    }
    int run = (t > 0) ? part[t - 1] : 0;
    for (int n = lo; n < hi; ++n) { offset[n] = run; run += count[n]; }
}

__global__ __launch_bounds__(256) void fill_elist(
    const int* __restrict__ eidx, const int* __restrict__ offset,
    int* __restrict__ cursor, int* __restrict__ elist)
{
    int e = blockIdx.x * 256 + threadIdx.x;
    int f = eidx[2*e];
    int p = atomicAdd(&cursor[f], 1);
    elist[offset[f] + p] = e;
}

// ---------------------------------------------------------------------------
// segment max: cf_b[n][ch] = bf16(max(0, max_{e: from[e]=n} msg[e][ch]))
// ---------------------------------------------------------------------------
__global__ __launch_bounds__(128) void segmax(
    const u16* __restrict__ msgb,   // [E,128] bf16
    const int* __restrict__ offset, const int* __restrict__ count,
    const int* __restrict__ elist,
    u16* __restrict__ cf_b)         // [N,128] bf16
{
    __shared__ int es[128];
    const int n = blockIdx.x;
    const int t = threadIdx.x;
    const int off = offset[n];
    const int deg = count[n];
    float m = 0.f;
    for (int s0 = 0; s0 < deg; s0 += 128) {
        int nd = min(128, deg - s0);
        __syncthreads();
        if (t < nd) es[t] = elist[off + s0 + t];
        __syncthreads();
        for (int d = 0; d < nd; ++d) {
            u16 u = msgb[(size_t)es[d]*HD + t];
            m = fmaxf(m, bf2f(u));
        }
    }
    cf_b[(size_t)n*HD + t] = f2bf(m);
}

// ---------------------------------------------------------------------------
// parent_feat = leaky([ipf0|ipf1|ipf2] @ second_w.T + second_b)
// ---------------------------------------------------------------------------
__global__ __launch_bounds__(128) void head_feat(
    const unsigned* __restrict__ ipf0_m,
    const float* __restrict__ ipf1, const float* __restrict__ ipf2,
    const float* __restrict__ W,    // [128,384]
    const float* __restrict__ bvec, float* __restrict__ out)
{
    __shared__ float s[384];
    const int t = threadIdx.x;
    s[t]       = funmap(ipf0_m[t]);
    s[128 + t] = ipf1[t];
    s[256 + t] = ipf2[t];
    __syncthreads();
    float acc = bvec[t];
    #pragma unroll 4
    for (int k = 0; k < 384; ++k) acc = fmaf(s[k], W[t*384 + k], acc);
    out[t] = leaky(acc);
}

// ---------------------------------------------------------------------------
// parent_geo = leaky(leaky(sg) + GN(leaky(pg) @ sgeo_w.T + sgeo_b) * gnw + gnb)
// ---------------------------------------------------------------------------
__global__ __launch_bounds__(128) void head_geo(
    const unsigned* __restrict__ pg_m, const unsigned* __restrict__ sg_m,
    const float* __restrict__ W,    // [128,128]
    const float* __restrict__ bvec,
    const float* __restrict__ gnw, const float* __restrict__ gnb,
    float* __restrict__ out)
{
    __shared__ float pg[128];
    __shared__ float tt[128];
    const int t = threadIdx.x;
    pg[t] = leaky(funmap(pg_m[t]));
    float sg = leaky(funmap(sg_m[t]));
    __syncthreads();
    float acc = bvec[t];
    #pragma unroll 4
    for (int k = 0; k < 128; ++k) acc = fmaf(pg[k], W[t*128 + k], acc);
    tt[t] = acc;
    __syncthreads();
    const int g = (t >> 3) << 3;
    float mu = 0.f, m2 = 0.f;
    #pragma unroll
    for (int q = 0; q < 8; ++q) { float x = tt[g + q]; mu += x; m2 += x*x; }
    mu *= 0.125f;
    m2 = m2 * 0.125f - mu * mu;
    float xn = (acc - mu) * rsqrtf(m2 + 1e-5f);
    out[t] = leaky(sg + xn * gnw[t] + gnb[t]);
}

// ---------------------------------------------------------------------------
extern "C" void kernel_launch(void* const* d_in, const int* in_sizes, int n_in,
                              void* d_out, int out_size, void* d_ws, size_t ws_size,
                              hipStream_t stream)
{
    const float* child_feats  = (const float*)d_in[0];
    const float* child_geo    = (const float*)d_in[1];
    const float* child_exists = (const float*)d_in[2];
    const float* etoh         = (const float*)d_in[3];
    const int*   eidx         = (const int*)  d_in[4];
    const float* op_w   = (const float*)d_in[5];
    const float* op_b   = (const float*)d_in[6];
    const float* sec_w  = (const float*)d_in[7];
    const float* sec_b  = (const float*)d_in[8];
    const float* edge_w = (const float*)d_in[9];
    const float* edge_b = (const float*)d_in[10];
    const float* geo_w  = (const float*)d_in[11];
    const float* geo_b  = (const float*)d_in[12];
    const float* sgeo_w = (const float*)d_in[13];
    const float* sgeo_b = (const float*)d_in[14];
    const float* gn_w   = (const float*)d_in[15];
    const float* gn_b   = (const float*)d_in[16];
    const float* skip_w = (const float*)d_in[17];
    const float* skip_b = (const float*)d_in[18];
    float* out = (float*)d_out;

    // workspace layout (all offsets 16B aligned)
    char* ws = (char*)d_ws;
    size_t off = 0;
    u16* cf_a  = (u16*)(ws + off); off += (size_t)N_NODES*HD*2;        // 5.12 MB
    u16* cf_b  = (u16*)(ws + off); off += (size_t)N_NODES*HD*2;        // 5.12 MB
    u16* msgb  = (u16*)(ws + off); off += (size_t)N_EDGES*HD*2;        // 81.92 MB
    u16* Wb    = (u16*)(ws + off); off += (size_t)2*128*KPAD*2;        // 147 KB
    int* elist = (int*)(ws + off); off += (size_t)N_EDGES*4;           // 1.28 MB
    int* offs  = (int*)(ws + off); off += (size_t)N_NODES*4;           // 80 KB
    char* zero0 = ws + off;
    unsigned* ipf0_m = (unsigned*)(ws + off); off += 128*4;
    float*    ipf1   = (float*)(ws + off);    off += 128*4;
    float*    ipf2   = (float*)(ws + off);    off += 128*4;
    unsigned* pg_m   = (unsigned*)(ws + off); off += 128*4;
    unsigned* sg_m   = (unsigned*)(ws + off); off += 128*4;
    int*      count  = (int*)(ws + off);      off += (size_t)N_NODES*4;
    int*      cursor = (int*)(ws + off);      off += (size_t)N_NODES*4;
    size_t zero_bytes = (size_t)(ws + off - zero0);

    hipMemsetAsync(zero0, 0, zero_bytes, stream);

    conv_w<<<2, 256, 0, stream>>>(edge_w, Wb);

    // CSR build (independent of GEMMs)
    hist_from<<<N_EDGES/256, 256, 0, stream>>>(eidx, count);
    scan_offsets<<<1, 256, 0, stream>>>(count, offs);
    fill_elist<<<N_EDGES/256, 256, 0, stream>>>(eidx, offs, cursor, elist);

    encode_nodes<<<(N_NODES + 127)/128, 256, 0, stream>>>(
        child_feats, child_exists, op_w, op_b, cf_a, ipf0_m);

    geo_nodes<<<dim3((N_NODES + 127)/128, 2), 256, 0, stream>>>(
        child_geo, child_exists, geo_w, geo_b, skip_w, skip_b, pg_m, sg_m);

    // iter 1: MFMA messages -> dense bf16 + column max
    edge_mfma<1><<<N_EDGES/128, 256, 0, stream>>>(
        cf_a, eidx, etoh, Wb, edge_b, msgb, (int*)ipf1);

    // segment max -> cf_b (bf16)
    segmax<<<N_NODES, 128, 0, stream>>>(msgb, offs, count, elist, cf_b);

    // iter 2: only column max needed
    edge_mfma<0><<<N_EDGES/128, 256, 0, stream>>>(
        cf_b, eidx, etoh, Wb + 128*KPAD, edge_b + 128, nullptr, (int*)ipf2);

    head_feat<<<1, 128, 0, stream>>>(ipf0_m, ipf1, ipf2, sec_w, sec_b, out);

    head_geo<<<1, 128, 0, stream>>>(pg_m, sg_m, sgeo_w, sgeo_b, gn_w, gn_b, out + 128);
}

// Round 4
// 478.866 us; speedup vs baseline: 2.8598x; 1.1337x over previous
//
#include <hip/hip_runtime.h>

#define N_NODES 20000
#define N_EDGES 320000
#define HD 128
#define FIN 162      // 24 + 10 + 128
#define KE 260       // 2*H + ETN
#define KPAD 288     // 9 chunks of 32 (256..259 = edge-type, rest zero)
#define ASTR 40      // LDS row stride (bf16 units): 80 B, conflict-benign for b128

typedef unsigned short u16;
typedef __attribute__((ext_vector_type(8))) short bf16x8;
typedef __attribute__((ext_vector_type(4))) float f32x4;

__device__ __forceinline__ float leaky(float x){ return x > 0.f ? x : 0.01f*x; }
__device__ __forceinline__ unsigned fmap(float f){
    unsigned u = __float_as_uint(f);
    return (u & 0x80000000u) ? ~u : (u | 0x80000000u);
}
__device__ __forceinline__ float funmap(unsigned u){
    return __uint_as_float((u & 0x80000000u) ? (u & 0x7fffffffu) : ~u);
}
__device__ __forceinline__ unsigned umax_(unsigned a, unsigned b){ return a > b ? a : b; }
__device__ __forceinline__ u16 f2bf(float x){
    unsigned b = __float_as_uint(x);
    return (u16)((b + 0x7fffu + ((b >> 16) & 1u)) >> 16);
}
__device__ __forceinline__ float bf2f(u16 u){
    return __uint_as_float(((unsigned)u) << 16);
}

// ---------------------------------------------------------------------------
// cf = bf16((child_feats @ op_w.T + op_b) * exists) ; ipf0_m = mapped colmax
// ---------------------------------------------------------------------------
__global__ __launch_bounds__(256) void encode_nodes(
    const float* __restrict__ feats,    // [N,162]
    const float* __restrict__ exists,   // [N]
    const float* __restrict__ W,        // [128,162]
    const float* __restrict__ bvec,     // [128]
    u16* __restrict__ cf,               // [N,128] bf16 out
    unsigned* __restrict__ ipf0_m)      // [128] mapped-uint accum (init 0)
{
    __shared__ float As[16][128];
    __shared__ float Bs[16][128];
    __shared__ float As2[2][128];
    __shared__ float Bs2[2][128];
    __shared__ float ex_s[128];
    __shared__ unsigned colmax[128];
    const int t  = threadIdx.x;
    const int tx = t & 15, ty = t >> 4;
    const int base = blockIdx.x * 128;

    if (t < 128) {
        int n = base + t; if (n >= N_NODES) n = N_NODES - 1;
        ex_s[t] = exists[n];
        colmax[t] = 0u;
        float2 v = *(const float2*)&feats[n*FIN + 160];
        As2[0][t] = v.x; As2[1][t] = v.y;
        float2 w = *(const float2*)&W[t*FIN + 160];
        Bs2[0][t] = w.x; Bs2[1][t] = w.y;
    }

    float acc[8][8];
    #pragma unroll
    for (int i = 0; i < 8; ++i)
        #pragma unroll
        for (int j = 0; j < 8; ++j) acc[i][j] = 0.f;

    for (int c = 0; c < 10; ++c) {
        const int kk = c * 16;
        __syncthreads();
        #pragma unroll
        for (int l = 0; l < 4; ++l) {
            int idx = l*256 + t;
            int m = idx & 127, kh = idx >> 7;
            int n = base + m; if (n >= N_NODES) n = N_NODES - 1;
            float2 v = *(const float2*)&feats[n*FIN + kk + kh*2];
            As[kh*2+0][m] = v.x; As[kh*2+1][m] = v.y;
        }
        #pragma unroll
        for (int l = 0; l < 4; ++l) {
            int idx = l*256 + t;
            int h = idx & 127, kh = idx >> 7;
            float2 v = *(const float2*)&W[h*FIN + kk + kh*2];
            Bs[kh*2+0][h] = v.x; Bs[kh*2+1][h] = v.y;
        }
        __syncthreads();
        #pragma unroll
        for (int k = 0; k < 16; ++k) {
            float4 a0 = *(const float4*)&As[k][ty*8];
            float4 a1 = *(const float4*)&As[k][ty*8+4];
            float4 b0 = *(const float4*)&Bs[k][tx*8];
            float4 b1 = *(const float4*)&Bs[k][tx*8+4];
            float av[8] = {a0.x,a0.y,a0.z,a0.w,a1.x,a1.y,a1.z,a1.w};
            float bv[8] = {b0.x,b0.y,b0.z,b0.w,b1.x,b1.y,b1.z,b1.w};
            #pragma unroll
            for (int i = 0; i < 8; ++i)
                #pragma unroll
                for (int j = 0; j < 8; ++j)
                    acc[i][j] = fmaf(av[i], bv[j], acc[i][j]);
        }
    }
    #pragma unroll
    for (int k = 0; k < 2; ++k) {
        float av[8], bv[8];
        #pragma unroll
        for (int i = 0; i < 8; ++i) av[i] = As2[k][ty*8+i];
        #pragma unroll
        for (int j = 0; j < 8; ++j) bv[j] = Bs2[k][tx*8+j];
        #pragma unroll
        for (int i = 0; i < 8; ++i)
            #pragma unroll
            for (int j = 0; j < 8; ++j)
                acc[i][j] = fmaf(av[i], bv[j], acc[i][j]);
    }

    float bias8[8];
    #pragma unroll
    for (int j = 0; j < 8; ++j) bias8[j] = bvec[tx*8+j];

    #pragma unroll
    for (int i = 0; i < 8; ++i) {
        int m = ty*8 + i; int n = base + m;
        float ex = ex_s[m];
        #pragma unroll
        for (int j = 0; j < 8; ++j) acc[i][j] = (acc[i][j] + bias8[j]) * ex;
        if (n < N_NODES) {
            union { u16 us[8]; uint4 v; } pk;
            #pragma unroll
            for (int j = 0; j < 8; ++j) pk.us[j] = f2bf(acc[i][j]);
            *(uint4*)&cf[n*HD + tx*8] = pk.v;
        }
    }
    #pragma unroll
    for (int j = 0; j < 8; ++j) {
        unsigned mx = 0u;
        #pragma unroll
        for (int i = 0; i < 8; ++i) mx = umax_(mx, fmap(acc[i][j]));
        atomicMax(&colmax[tx*8+j], mx);
    }
    __syncthreads();
    if (t < 128) atomicMax(&ipf0_m[t], colmax[t]);
}

// ---------------------------------------------------------------------------
// geo pass: colmax of (geo @ Wy.T + by) * exists for y in {child_geo, skip}
// ---------------------------------------------------------------------------
__global__ __launch_bounds__(256) void geo_nodes(
    const float* __restrict__ feats,    // [N,128]
    const float* __restrict__ exists,
    const float* __restrict__ W0, const float* __restrict__ b0,
    const float* __restrict__ W1, const float* __restrict__ b1,
    unsigned* __restrict__ acc0, unsigned* __restrict__ acc1)
{
    const float* W  = blockIdx.y ? W1 : W0;
    const float* bv = blockIdx.y ? b1 : b0;
    unsigned* accout = blockIdx.y ? acc1 : acc0;

    __shared__ float As[16][128];
    __shared__ float Bs[16][128];
    __shared__ float ex_s[128];
    __shared__ unsigned colmax[128];
    const int t  = threadIdx.x;
    const int tx = t & 15, ty = t >> 4;
    const int base = blockIdx.x * 128;

    if (t < 128) {
        int n = base + t; if (n >= N_NODES) n = N_NODES - 1;
        ex_s[t] = exists[n];
        colmax[t] = 0u;
    }
    float acc[8][8];
    #pragma unroll
    for (int i = 0; i < 8; ++i)
        #pragma unroll
        for (int j = 0; j < 8; ++j) acc[i][j] = 0.f;

    for (int c = 0; c < 8; ++c) {
        const int kk = c * 16;
        __syncthreads();
        #pragma unroll
        for (int l = 0; l < 2; ++l) {
            int idx = l*256 + t;
            int m = idx & 127, kq = idx >> 7;
            int n = base + m; if (n >= N_NODES) n = N_NODES - 1;
            float4 v = *(const float4*)&feats[n*HD + kk + kq*4];
            As[kq*4+0][m]=v.x; As[kq*4+1][m]=v.y; As[kq*4+2][m]=v.z; As[kq*4+3][m]=v.w;
        }
        #pragma unroll
        for (int l = 0; l < 2; ++l) {
            int idx = l*256 + t;
            int h = idx & 127, kq = idx >> 7;
            float4 v = *(const float4*)&W[h*HD + kk + kq*4];
            Bs[kq*4+0][h]=v.x; Bs[kq*4+1][h]=v.y; Bs[kq*4+2][h]=v.z; Bs[kq*4+3][h]=v.w;
        }
        __syncthreads();
        #pragma unroll
        for (int k = 0; k < 16; ++k) {
            float4 a0 = *(const float4*)&As[k][ty*8];
            float4 a1 = *(const float4*)&As[k][ty*8+4];
            float4 b0 = *(const float4*)&Bs[k][tx*8];
            float4 b1 = *(const float4*)&Bs[k][tx*8+4];
            float av[8] = {a0.x,a0.y,a0.z,a0.w,a1.x,a1.y,a1.z,a1.w};
            float bvv[8] = {b0.x,b0.y,b0.z,b0.w,b1.x,b1.y,b1.z,b1.w};
            #pragma unroll
            for (int i = 0; i < 8; ++i)
                #pragma unroll
                for (int j = 0; j < 8; ++j)
                    acc[i][j] = fmaf(av[i], bvv[j], acc[i][j]);
        }
    }

    float bias8[8];
    #pragma unroll
    for (int j = 0; j < 8; ++j) bias8[j] = bv[tx*8+j];
    #pragma unroll
    for (int j = 0; j < 8; ++j) {
        unsigned mx = 0u;
        #pragma unroll
        for (int i = 0; i < 8; ++i) {
            float v = (acc[i][j] + bias8[j]) * ex_s[ty*8+i];
            mx = umax_(mx, fmap(v));
        }
        atomicMax(&colmax[tx*8+j], mx);
    }
    __syncthreads();
    if (t < 128) atomicMax(&accout[t], colmax[t]);
}

// ---------------------------------------------------------------------------
// fused: blocks 0,1 = weight convert (layer b) ; blocks 2.. = from-histogram
// ---------------------------------------------------------------------------
__global__ __launch_bounds__(256) void conv_hist(
    const float* __restrict__ w, u16* __restrict__ Wb,
    const int* __restrict__ eidx, int* __restrict__ count)
{
    const int b = blockIdx.x;
    if (b < 2) {
        const float* src = w + (size_t)b * 128 * KE;
        u16* dst = Wb + (size_t)b * 128 * KPAD;
        for (int i = threadIdx.x; i < 128 * KPAD; i += 256) {
            int h = i / KPAD, k = i - h * KPAD;
            dst[i] = (k < KE) ? f2bf(src[h * KE + k]) : (u16)0;
        }
    } else {
        int e = (b - 2) * 256 + threadIdx.x;
        atomicAdd(&count[eidx[2*e]], 1);
    }
}

__global__ __launch_bounds__(256) void scan_offsets(
    const int* __restrict__ count, int* __restrict__ offset)
{
    __shared__ int part[256];
    const int t = threadIdx.x;
    const int lo = t * 79;
    const int hi = min(lo + 79, N_NODES);
    int s = 0;
    for (int n = lo; n < hi; ++n) s += count[n];
    part[t] = s;
    __syncthreads();
    for (int d = 1; d < 256; d <<= 1) {
        int v = (t >= d) ? part[t - d] : 0;
        __syncthreads();
        part[t] += v;
        __syncthreads();
    }
    int run = (t > 0) ? part[t - 1] : 0;
    for (int n = lo; n < hi; ++n) { offset[n] = run; run += count[n]; }
}

// fill permuted edge arrays in CSR (from-sorted) order
__global__ __launch_bounds__(256) void fill_perm(
    const int* __restrict__ eidx, const float* __restrict__ ef,
    const int* __restrict__ offset, int* __restrict__ cursor,
    int* __restrict__ from_p, int* __restrict__ to_p, uint2* __restrict__ efb_p)
{
    int e = blockIdx.x * 256 + threadIdx.x;
    int2 p = ((const int2*)eidx)[e];
    int pos = offset[p.x] + atomicAdd(&cursor[p.x], 1);
    from_p[pos] = p.x; to_p[pos] = p.y;
    float4 e4 = ((const float4*)ef)[e];
    efb_p[pos] = make_uint2(
        (unsigned)f2bf(e4.x) | ((unsigned)f2bf(e4.y) << 16),
        (unsigned)f2bf(e4.z) | ((unsigned)f2bf(e4.w) << 16));
}

// ---------------------------------------------------------------------------
// MFMA edge pass on CSR-permuted edges: msg = leaky([cf[f]|cf[t]|ef]@W.T + b)
// 256 edges x 128 ch per block; 8 waves in 4x2 grid (64x64 each); K = 9x32
// STORE_MSG: msgb[pos][h] = bf16(msg)  (CSR order -> segmax reads contiguous)
// ---------------------------------------------------------------------------
template<int STORE_MSG>
__global__ __launch_bounds__(512, 4) void edge_mfma(
    const u16* __restrict__ cfb,       // [N,128] bf16
    const int* __restrict__ from_p,    // [E] sorted
    const int* __restrict__ to_p,      // [E] permuted
    const uint2* __restrict__ efb_p,   // [E] 4x bf16 packed
    const u16* __restrict__ Wb,        // [128,288] bf16 (padded)
    const float* __restrict__ bias,    // [128]
    u16* __restrict__ msgb,            // [E,128] bf16 (CSR order)
    int* __restrict__ ipf_out)         // [128]
{
    __shared__ __align__(16) u16 As[2][256 * ASTR];
    __shared__ __align__(16) u16 Bs[2][128 * ASTR];
    __shared__ int colmax_s[128];

    const int t    = threadIdx.x;
    const int base = blockIdx.x * 256;        // 1250 blocks exact
    const int wave = t >> 6, l = t & 63;
    const int quad = l >> 4, lc = l & 15;
    const int R0 = (wave >> 1) * 64;          // 4 wave-rows
    const int C0 = (wave & 1) * 64;           // 2 wave-cols
    const bool isA = (t < 256);               // waves 0-3 stage A; 4-7 stage B

    // per-stager edge metadata lives in registers (rows are contiguous)
    int nf = 0, nt = 0; uint2 efr = make_uint2(0, 0);
    if (isA) {
        nf  = from_p[base + t];
        nt  = to_p[base + t];
        efr = efb_p[base + t];
    }
    if (t < 128) colmax_s[t] = 0;

    uint4 pref[4];
    auto prefetch = [&](int c) {
        if (isA) {
            if (c < 8) {
                int node = (c < 4) ? nf : nt;
                const uint4* src = (const uint4*)(cfb + node * HD + (c & 3) * 32);
                pref[0] = src[0]; pref[1] = src[1]; pref[2] = src[2]; pref[3] = src[3];
            } else {
                pref[0] = make_uint4(efr.x, efr.y, 0u, 0u);
                pref[1] = make_uint4(0,0,0,0);
                pref[2] = make_uint4(0,0,0,0);
                pref[3] = make_uint4(0,0,0,0);
            }
        } else {
            int row = (t - 256) >> 1, half = (t & 1) * 2;  // uint4 index
            const uint4* src = (const uint4*)(Wb + row * KPAD + c * 32) + half;
            pref[0] = src[0]; pref[1] = src[1];
        }
    };
    auto commit = [&](int c) {
        if (isA) {
            u16* dst = As[c & 1] + t * ASTR;
            *(uint4*)(dst +  0) = pref[0];
            *(uint4*)(dst +  8) = pref[1];
            *(uint4*)(dst + 16) = pref[2];
            *(uint4*)(dst + 24) = pref[3];
        } else {
            int row = (t - 256) >> 1;
            u16* dst = Bs[c & 1] + row * ASTR + (t & 1) * 16;
            *(uint4*)(dst + 0) = pref[0];
            *(uint4*)(dst + 8) = pref[1];
        }
    };

    prefetch(0); commit(0);
    __syncthreads();

    f32x4 acc[4][4];
    #pragma unroll
    for (int i = 0; i < 4; ++i)
        #pragma unroll
        for (int j = 0; j < 4; ++j) acc[i][j] = (f32x4){0.f, 0.f, 0.f, 0.f};

    for (int c = 0; c < 9; ++c) {
        if (c < 8) prefetch(c + 1);
        const u16* Ab = As[c & 1] + (R0 + lc) * ASTR + quad * 8;
        const u16* Bb = Bs[c & 1] + (C0 + lc) * ASTR + quad * 8;
        bf16x8 af[4], bfr[4];
        #pragma unroll
        for (int ti = 0; ti < 4; ++ti) af[ti]  = *(const bf16x8*)(Ab + ti * 16 * ASTR);
        #pragma unroll
        for (int tj = 0; tj < 4; ++tj) bfr[tj] = *(const bf16x8*)(Bb + tj * 16 * ASTR);
        #pragma unroll
        for (int ti = 0; ti < 4; ++ti)
            #pragma unroll
            for (int tj = 0; tj < 4; ++tj)
                acc[ti][tj] = __builtin_amdgcn_mfma_f32_16x16x32_bf16(
                    af[ti], bfr[tj], acc[ti][tj], 0, 0, 0);
        if (c < 8) { commit(c + 1); __syncthreads(); }
    }

    // epilogue: bias + leaky, column max, optional bf16 message store
    #pragma unroll
    for (int tj = 0; tj < 4; ++tj) {
        const int col = C0 + tj * 16 + lc;
        const float bc = bias[col];
        float mx = 0.f;
        #pragma unroll
        for (int ti = 0; ti < 4; ++ti) {
            f32x4 v = acc[ti][tj];
            #pragma unroll
            for (int r = 0; r < 4; ++r) {
                float x = leaky(v[r] + bc);
                if (STORE_MSG)
                    msgb[(size_t)(base + R0 + ti * 16 + quad * 4 + r) * HD + col] = f2bf(x);
                mx = fmaxf(mx, x);
            }
        }
        atomicMax(&colmax_s[col], __float_as_int(mx));   // mx >= 0: int-bits OK
    }
    __syncthreads();
    if (t < 128) atomicMax(&ipf_out[t], colmax_s[t]);
}

// ---------------------------------------------------------------------------
// segment max over CSR-contiguous message rows:
//   cf_b[n][ch] = bf16(max(0, max_{pos in [off,off+deg)} msg[pos][ch]))
// two nodes per 256-thread block
// ---------------------------------------------------------------------------
__global__ __launch_bounds__(256) void segmax(
    const u16* __restrict__ msgb,   // [E,128] bf16, CSR order
    const int* __restrict__ offset, const int* __restrict__ count,
    u16* __restrict__ cf_b)         // [N,128] bf16
{
    const int n = blockIdx.x * 2 + (threadIdx.x >> 7);
    const int t = threadIdx.x & 127;
    const int off = offset[n];
    const int deg = count[n];
    float m = 0.f;
    const u16* p = msgb + (size_t)off * HD + t;
    for (int d = 0; d < deg; ++d) m = fmaxf(m, bf2f(p[(size_t)d * HD]));
    cf_b[(size_t)n * HD + t] = f2bf(m);
}

// ---------------------------------------------------------------------------
// fused heads: block 0 = parent_feat, block 1 = parent_geo
// ---------------------------------------------------------------------------
__global__ __launch_bounds__(128) void heads(
    const unsigned* __restrict__ ipf0_m,
    const float* __restrict__ ipf1, const float* __restrict__ ipf2,
    const float* __restrict__ secW, const float* __restrict__ secB,
    const unsigned* __restrict__ pg_m, const unsigned* __restrict__ sg_m,
    const float* __restrict__ geoW, const float* __restrict__ geoB,
    const float* __restrict__ gnw, const float* __restrict__ gnb,
    float* __restrict__ out)
{
    const int t = threadIdx.x;
    if (blockIdx.x == 0) {
        __shared__ float s[384];
        s[t]       = funmap(ipf0_m[t]);
        s[128 + t] = ipf1[t];
        s[256 + t] = ipf2[t];
        __syncthreads();
        float acc = secB[t];
        #pragma unroll 4
        for (int k = 0; k < 384; ++k) acc = fmaf(s[k], secW[t*384 + k], acc);
        out[t] = leaky(acc);
    } else {
        __shared__ float pg[128];
        __shared__ float tt[128];
        pg[t] = leaky(funmap(pg_m[t]));
        float sg = leaky(funmap(sg_m[t]));
        __syncthreads();
        float acc = geoB[t];
        #pragma unroll 4
        for (int k = 0; k < 128; ++k) acc = fmaf(pg[k], geoW[t*128 + k], acc);
        tt[t] = acc;
        __syncthreads();
        const int g = (t >> 3) << 3;
        float mu = 0.f, m2 = 0.f;
        #pragma unroll
        for (int q = 0; q < 8; ++q) { float x = tt[g + q]; mu += x; m2 += x*x; }
        mu *= 0.125f;
        m2 = m2 * 0.125f - mu * mu;
        float xn = (acc - mu) * rsqrtf(m2 + 1e-5f);
        out[128 + t] = leaky(sg + xn * gnw[t] + gnb[t]);
    }
}

// ---------------------------------------------------------------------------
extern "C" void kernel_launch(void* const* d_in, const int* in_sizes, int n_in,
                              void* d_out, int out_size, void* d_ws, size_t ws_size,
                              hipStream_t stream)
{
    const float* child_feats  = (const float*)d_in[0];
    const float* child_geo    = (const float*)d_in[1];
    const float* child_exists = (const float*)d_in[2];
    const float* etoh         = (const float*)d_in[3];
    const int*   eidx         = (const int*)  d_in[4];
    const float* op_w   = (const float*)d_in[5];
    const float* op_b   = (const float*)d_in[6];
    const float* sec_w  = (const float*)d_in[7];
    const float* sec_b  = (const float*)d_in[8];
    const float* edge_w = (const float*)d_in[9];
    const float* edge_b = (const float*)d_in[10];
    const float* geo_w  = (const float*)d_in[11];
    const float* geo_b  = (const float*)d_in[12];
    const float* sgeo_w = (const float*)d_in[13];
    const float* sgeo_b = (const float*)d_in[14];
    const float* gn_w   = (const float*)d_in[15];
    const float* gn_b   = (const float*)d_in[16];
    const float* skip_w = (const float*)d_in[17];
    const float* skip_b = (const float*)d_in[18];
    float* out = (float*)d_out;

    // workspace layout (all offsets 16B aligned)
    char* ws = (char*)d_ws;
    size_t off = 0;
    u16*   cf_a   = (u16*)(ws + off);   off += (size_t)N_NODES*HD*2;    // 5.12 MB
    u16*   cf_b   = (u16*)(ws + off);   off += (size_t)N_NODES*HD*2;    // 5.12 MB
    u16*   msgb   = (u16*)(ws + off);   off += (size_t)N_EDGES*HD*2;    // 81.92 MB
    u16*   Wb     = (u16*)(ws + off);   off += (size_t)2*128*KPAD*2;    // 147 KB
    int*   from_p = (int*)(ws + off);   off += (size_t)N_EDGES*4;       // 1.28 MB
    int*   to_p   = (int*)(ws + off);   off += (size_t)N_EDGES*4;       // 1.28 MB
    uint2* efb_p  = (uint2*)(ws + off); off += (size_t)N_EDGES*8;       // 2.56 MB
    int*   offs   = (int*)(ws + off);   off += (size_t)N_NODES*4;       // 80 KB
    char*  zero0  = ws + off;
    unsigned* ipf0_m = (unsigned*)(ws + off); off += 128*4;
    float*    ipf1   = (float*)(ws + off);    off += 128*4;
    float*    ipf2   = (float*)(ws + off);    off += 128*4;
    unsigned* pg_m   = (unsigned*)(ws + off); off += 128*4;
    unsigned* sg_m   = (unsigned*)(ws + off); off += 128*4;
    int*      count  = (int*)(ws + off);      off += (size_t)N_NODES*4;
    int*      cursor = (int*)(ws + off);      off += (size_t)N_NODES*4;
    size_t zero_bytes = (size_t)(ws + off - zero0);

    hipMemsetAsync(zero0, 0, zero_bytes, stream);

    // weight convert (blocks 0,1) + from-histogram (blocks 2..)
    conv_hist<<<2 + N_EDGES/256, 256, 0, stream>>>(edge_w, Wb, eidx, count);

    scan_offsets<<<1, 256, 0, stream>>>(count, offs);

    fill_perm<<<N_EDGES/256, 256, 0, stream>>>(
        eidx, etoh, offs, cursor, from_p, to_p, efb_p);

    encode_nodes<<<(N_NODES + 127)/128, 256, 0, stream>>>(
        child_feats, child_exists, op_w, op_b, cf_a, ipf0_m);

    geo_nodes<<<dim3((N_NODES + 127)/128, 2), 256, 0, stream>>>(
        child_geo, child_exists, geo_w, geo_b, skip_w, skip_b, pg_m, sg_m);

    // iter 1: MFMA messages (CSR order) -> dense bf16 + column max
    edge_mfma<1><<<N_EDGES/256, 512, 0, stream>>>(
        cf_a, from_p, to_p, efb_p, Wb, edge_b, msgb, (int*)ipf1);

    // contiguous segment max -> cf_b (bf16)
    segmax<<<N_NODES/2, 256, 0, stream>>>(msgb, offs, count, cf_b);

    // iter 2: only column max needed
    edge_mfma<0><<<N_EDGES/256, 512, 0, stream>>>(
        cf_b, from_p, to_p, efb_p, Wb + 128*KPAD, edge_b + 128, nullptr, (int*)ipf2);

    heads<<<2, 128, 0, stream>>>(ipf0_m, ipf1, ipf2, sec_w, sec_b,
                                 pg_m, sg_m, sgeo_w, sgeo_b, gn_w, gn_b, out);
}

// Round 5
// 395.731 us; speedup vs baseline: 3.4606x; 1.2101x over previous
//
#include <hip/hip_runtime.h>

#define N_NODES 20000
#define N_EDGES 320000
#define HD 128
#define FIN 162      // 24 + 10 + 128
#define KE 260       // 2*H + ETN
#define KPAD 288     // 9 chunks of 32 (256..259 = edge-type, rest zero)
#define TSTR 136     // transpose-buffer row stride (u16): 272 B, 16B-aligned

typedef unsigned short u16;
typedef __attribute__((ext_vector_type(8))) short bf16x8;
typedef __attribute__((ext_vector_type(4))) float f32x4;

__device__ __forceinline__ float leaky(float x){ return x > 0.f ? x : 0.01f*x; }
__device__ __forceinline__ unsigned fmap(float f){
    unsigned u = __float_as_uint(f);
    return (u & 0x80000000u) ? ~u : (u | 0x80000000u);
}
__device__ __forceinline__ float funmap(unsigned u){
    return __uint_as_float((u & 0x80000000u) ? (u & 0x7fffffffu) : ~u);
}
__device__ __forceinline__ unsigned umax_(unsigned a, unsigned b){ return a > b ? a : b; }
__device__ __forceinline__ u16 f2bf(float x){
    unsigned b = __float_as_uint(x);
    return (u16)((b + 0x7fffu + ((b >> 16) & 1u)) >> 16);
}
__device__ __forceinline__ float bf2f(u16 u){
    return __uint_as_float(((unsigned)u) << 16);
}

// ---------------------------------------------------------------------------
// device bodies for the fused front launch
// ---------------------------------------------------------------------------
__device__ void conv_w_dev(const float* __restrict__ w, u16* __restrict__ Wb, int layer)
{
    const float* src = w + (size_t)layer * 128 * KE;
    u16* dst = Wb + (size_t)layer * 128 * KPAD;
    for (int i = threadIdx.x; i < 128 * KPAD; i += 256) {
        int h = i / KPAD, k = i - h * KPAD;
        dst[i] = (k < KE) ? f2bf(src[h * KE + k]) : (u16)0;
    }
}

// cf = bf16((child_feats @ op_w.T + op_b) * exists) ; ipf0_m = mapped colmax
__device__ void encode_dev(char* sh, int bx,
    const float* __restrict__ feats, const float* __restrict__ exists,
    const float* __restrict__ W, const float* __restrict__ bvec,
    u16* __restrict__ cf, unsigned* __restrict__ ipf0_m)
{
    float (*As)[128]  = (float(*)[128])(sh);          // 16x128
    float (*Bs)[128]  = (float(*)[128])(sh + 8192);   // 16x128
    float (*As2)[128] = (float(*)[128])(sh + 16384);  // 2x128
    float (*Bs2)[128] = (float(*)[128])(sh + 17408);  // 2x128
    float* ex_s       = (float*)(sh + 18432);         // 128
    unsigned* colmax  = (unsigned*)(sh + 18944);      // 128

    const int t  = threadIdx.x;
    const int tx = t & 15, ty = t >> 4;
    const int base = bx * 128;

    if (t < 128) {
        int n = base + t; if (n >= N_NODES) n = N_NODES - 1;
        ex_s[t] = exists[n];
        colmax[t] = 0u;
        float2 v = *(const float2*)&feats[n*FIN + 160];
        As2[0][t] = v.x; As2[1][t] = v.y;
        float2 w = *(const float2*)&W[t*FIN + 160];
        Bs2[0][t] = w.x; Bs2[1][t] = w.y;
    }

    float acc[8][8];
    #pragma unroll
    for (int i = 0; i < 8; ++i)
        #pragma unroll
        for (int j = 0; j < 8; ++j) acc[i][j] = 0.f;

    for (int c = 0; c < 10; ++c) {
        const int kk = c * 16;
        __syncthreads();
        #pragma unroll
        for (int l = 0; l < 4; ++l) {
            int idx = l*256 + t;
            int m = idx & 127, kh = idx >> 7;
            int n = base + m; if (n >= N_NODES) n = N_NODES - 1;
            float2 v = *(const float2*)&feats[n*FIN + kk + kh*2];
            As[kh*2+0][m] = v.x; As[kh*2+1][m] = v.y;
        }
        #pragma unroll
        for (int l = 0; l < 4; ++l) {
            int idx = l*256 + t;
            int h = idx & 127, kh = idx >> 7;
            float2 v = *(const float2*)&W[h*FIN + kk + kh*2];
            Bs[kh*2+0][h] = v.x; Bs[kh*2+1][h] = v.y;
        }
        __syncthreads();
        #pragma unroll
        for (int k = 0; k < 16; ++k) {
            float4 a0 = *(const float4*)&As[k][ty*8];
            float4 a1 = *(const float4*)&As[k][ty*8+4];
            float4 b0 = *(const float4*)&Bs[k][tx*8];
            float4 b1 = *(const float4*)&Bs[k][tx*8+4];
            float av[8] = {a0.x,a0.y,a0.z,a0.w,a1.x,a1.y,a1.z,a1.w};
            float bv[8] = {b0.x,b0.y,b0.z,b0.w,b1.x,b1.y,b1.z,b1.w};
            #pragma unroll
            for (int i = 0; i < 8; ++i)
                #pragma unroll
                for (int j = 0; j < 8; ++j)
                    acc[i][j] = fmaf(av[i], bv[j], acc[i][j]);
        }
    }
    #pragma unroll
    for (int k = 0; k < 2; ++k) {
        float av[8], bv[8];
        #pragma unroll
        for (int i = 0; i < 8; ++i) av[i] = As2[k][ty*8+i];
        #pragma unroll
        for (int j = 0; j < 8; ++j) bv[j] = Bs2[k][tx*8+j];
        #pragma unroll
        for (int i = 0; i < 8; ++i)
            #pragma unroll
            for (int j = 0; j < 8; ++j)
                acc[i][j] = fmaf(av[i], bv[j], acc[i][j]);
    }

    float bias8[8];
    #pragma unroll
    for (int j = 0; j < 8; ++j) bias8[j] = bvec[tx*8+j];

    #pragma unroll
    for (int i = 0; i < 8; ++i) {
        int m = ty*8 + i; int n = base + m;
        float ex = ex_s[m];
        #pragma unroll
        for (int j = 0; j < 8; ++j) acc[i][j] = (acc[i][j] + bias8[j]) * ex;
        if (n < N_NODES) {
            union { u16 us[8]; uint4 v; } pk;
            #pragma unroll
            for (int j = 0; j < 8; ++j) pk.us[j] = f2bf(acc[i][j]);
            *(uint4*)&cf[n*HD + tx*8] = pk.v;
        }
    }
    #pragma unroll
    for (int j = 0; j < 8; ++j) {
        unsigned mx = 0u;
        #pragma unroll
        for (int i = 0; i < 8; ++i) mx = umax_(mx, fmap(acc[i][j]));
        atomicMax(&colmax[tx*8+j], mx);
    }
    __syncthreads();
    if (t < 128) atomicMax(&ipf0_m[t], colmax[t]);
}

// colmax of (geo @ Wy.T + by) * exists for y in {child_geo, skip}
__device__ void geo_dev(char* sh, int bx, int which,
    const float* __restrict__ feats, const float* __restrict__ exists,
    const float* __restrict__ W0, const float* __restrict__ b0,
    const float* __restrict__ W1, const float* __restrict__ b1,
    unsigned* __restrict__ acc0, unsigned* __restrict__ acc1)
{
    const float* W  = which ? W1 : W0;
    const float* bv = which ? b1 : b0;
    unsigned* accout = which ? acc1 : acc0;

    float (*As)[128] = (float(*)[128])(sh);          // 16x128
    float (*Bs)[128] = (float(*)[128])(sh + 8192);   // 16x128
    float* ex_s      = (float*)(sh + 16384);
    unsigned* colmax = (unsigned*)(sh + 16896);

    const int t  = threadIdx.x;
    const int tx = t & 15, ty = t >> 4;
    const int base = bx * 128;

    if (t < 128) {
        int n = base + t; if (n >= N_NODES) n = N_NODES - 1;
        ex_s[t] = exists[n];
        colmax[t] = 0u;
    }
    float acc[8][8];
    #pragma unroll
    for (int i = 0; i < 8; ++i)
        #pragma unroll
        for (int j = 0; j < 8; ++j) acc[i][j] = 0.f;

    for (int c = 0; c < 8; ++c) {
        const int kk = c * 16;
        __syncthreads();
        #pragma unroll
        for (int l = 0; l < 2; ++l) {
            int idx = l*256 + t;
            int m = idx & 127, kq = idx >> 7;
            int n = base + m; if (n >= N_NODES) n = N_NODES - 1;
            float4 v = *(const float4*)&feats[n*HD + kk + kq*4];
            As[kq*4+0][m]=v.x; As[kq*4+1][m]=v.y; As[kq*4+2][m]=v.z; As[kq*4+3][m]=v.w;
        }
        #pragma unroll
        for (int l = 0; l < 2; ++l) {
            int idx = l*256 + t;
            int h = idx & 127, kq = idx >> 7;
            float4 v = *(const float4*)&W[h*HD + kk + kq*4];
            Bs[kq*4+0][h]=v.x; Bs[kq*4+1][h]=v.y; Bs[kq*4+2][h]=v.z; Bs[kq*4+3][h]=v.w;
        }
        __syncthreads();
        #pragma unroll
        for (int k = 0; k < 16; ++k) {
            float4 a0 = *(const float4*)&As[k][ty*8];
            float4 a1 = *(const float4*)&As[k][ty*8+4];
            float4 b0 = *(const float4*)&Bs[k][tx*8];
            float4 b1 = *(const float4*)&Bs[k][tx*8+4];
            float av[8] = {a0.x,a0.y,a0.z,a0.w,a1.x,a1.y,a1.z,a1.w};
            float bvv[8] = {b0.x,b0.y,b0.z,b0.w,b1.x,b1.y,b1.z,b1.w};
            #pragma unroll
            for (int i = 0; i < 8; ++i)
                #pragma unroll
                for (int j = 0; j < 8; ++j)
                    acc[i][j] = fmaf(av[i], bvv[j], acc[i][j]);
        }
    }

    float bias8[8];
    #pragma unroll
    for (int j = 0; j < 8; ++j) bias8[j] = bv[tx*8+j];
    #pragma unroll
    for (int j = 0; j < 8; ++j) {
        unsigned mx = 0u;
        #pragma unroll
        for (int i = 0; i < 8; ++i) {
            float v = (acc[i][j] + bias8[j]) * ex_s[ty*8+i];
            mx = umax_(mx, fmap(v));
        }
        atomicMax(&colmax[tx*8+j], mx);
    }
    __syncthreads();
    if (t < 128) atomicMax(&accout[t], colmax[t]);
}

// fused: [0,2) conv_w | [2,1252) from-histogram | [1252,1409) encode | [1409,1723) geo
__global__ __launch_bounds__(256) void fused_front(
    const float* __restrict__ edge_w, u16* __restrict__ Wb,
    const int* __restrict__ eidx, int* __restrict__ count,
    const float* __restrict__ child_feats, const float* __restrict__ child_exists,
    const float* __restrict__ op_w, const float* __restrict__ op_b,
    u16* __restrict__ cf_a, unsigned* __restrict__ ipf0_m,
    const float* __restrict__ child_geo,
    const float* __restrict__ geo_w, const float* __restrict__ geo_b,
    const float* __restrict__ skip_w, const float* __restrict__ skip_b,
    unsigned* __restrict__ pg_m, unsigned* __restrict__ sg_m)
{
    __shared__ __align__(16) char sh[19456];
    const int b = blockIdx.x;
    if (b < 2) {
        conv_w_dev(edge_w, Wb, b);
    } else if (b < 1252) {
        int e = (b - 2) * 256 + threadIdx.x;
        atomicAdd(&count[eidx[2*e]], 1);
    } else if (b < 1409) {
        encode_dev(sh, b - 1252, child_feats, child_exists, op_w, op_b, cf_a, ipf0_m);
    } else {
        int g = b - 1409;
        int which = (g >= 157) ? 1 : 0;
        geo_dev(sh, which ? g - 157 : g, which,
                child_geo, child_exists, geo_w, geo_b, skip_w, skip_b, pg_m, sg_m);
    }
}

// ---------------------------------------------------------------------------
__global__ __launch_bounds__(1024) void scan_offsets(
    const int* __restrict__ count, int* __restrict__ offset)
{
    __shared__ int part[1024];
    const int t = threadIdx.x;
    const int lo = t * 20;
    const int hi = min(lo + 20, N_NODES);
    int s = 0;
    for (int n = lo; n < hi; ++n) s += count[n];
    part[t] = s;
    __syncthreads();
    for (int d = 1; d < 1024; d <<= 1) {
        int v = (t >= d) ? part[t - d] : 0;
        __syncthreads();
        part[t] += v;
        __syncthreads();
    }
    int run = (t > 0) ? part[t - 1] : 0;
    for (int n = lo; n < hi; ++n) { offset[n] = run; run += count[n]; }
}

// fill permuted edge arrays in CSR (from-sorted) order
__global__ __launch_bounds__(256) void fill_perm(
    const int* __restrict__ eidx, const float* __restrict__ ef,
    const int* __restrict__ offset, int* __restrict__ cursor,
    int* __restrict__ from_p, int* __restrict__ to_p, uint2* __restrict__ efb_p)
{
    int e = blockIdx.x * 256 + threadIdx.x;
    int2 p = ((const int2*)eidx)[e];
    int pos = offset[p.x] + atomicAdd(&cursor[p.x], 1);
    from_p[pos] = p.x; to_p[pos] = p.y;
    float4 e4 = ((const float4*)ef)[e];
    efb_p[pos] = make_uint2(
        (unsigned)f2bf(e4.x) | ((unsigned)f2bf(e4.y) << 16),
        (unsigned)f2bf(e4.z) | ((unsigned)f2bf(e4.w) << 16));
}

// ---------------------------------------------------------------------------
// MFMA edge pass on CSR-permuted edges: msg = leaky([cf[f]|cf[t]|ef]@W.T + b)
// 256 edges x 128 ch per block; 8 waves in 4x2 grid (64x64 each); K = 9x32
// smem panes (u16 units): As[2] @0/@8192 (256x32), Bs[2] @16384/@20480 (128x32)
// Staging writes & ds_read_b128 are exactly conflict-free (chunk panes contiguous).
// STORE_MSG: LDS-transpose epilogue -> fully coalesced uint4 row stores.
// ---------------------------------------------------------------------------
template<int STORE_MSG>
__global__ __launch_bounds__(512, 4) void edge_mfma(
    const u16* __restrict__ cfb,       // [N,128] bf16
    const int* __restrict__ from_p,    // [E] sorted
    const int* __restrict__ to_p,      // [E] permuted
    const uint2* __restrict__ efb_p,   // [E] 4x bf16 packed
    const u16* __restrict__ Wb,        // [128,288] bf16 (padded)
    const float* __restrict__ bias,    // [128]
    u16* __restrict__ msgb,            // [E,128] bf16 (CSR order)
    int* __restrict__ ipf_out)         // [128]
{
    __shared__ __align__(16) u16 smem[24576];   // 49152 B
    __shared__ int colmax_s[128];

    const int t    = threadIdx.x;
    const int base = blockIdx.x * 256;          // 1250 blocks exact
    const int wave = t >> 6, l = t & 63;
    const int quad = l >> 4, lc = l & 15;
    const int R0 = (wave >> 1) * 64;
    const int C0 = (wave & 1) * 64;
    const bool isA = (t < 256);

    int nf = 0, nt2 = 0; uint2 efr = make_uint2(0, 0);
    if (isA) {
        nf  = from_p[base + t];
        nt2 = to_p[base + t];
        efr = efb_p[base + t];
    }
    if (t < 128) colmax_s[t] = 0;

    uint4 pref[4];
    auto prefetch = [&](int c) {
        if (isA) {
            if (c < 8) {
                int node = (c < 4) ? nf : nt2;
                const uint4* src = (const uint4*)(cfb + node * HD + (c & 3) * 32);
                pref[0] = src[0]; pref[1] = src[1]; pref[2] = src[2]; pref[3] = src[3];
            } else {
                pref[0] = make_uint4(efr.x, efr.y, 0u, 0u);
                pref[1] = make_uint4(0,0,0,0);
                pref[2] = make_uint4(0,0,0,0);
                pref[3] = make_uint4(0,0,0,0);
            }
        } else {
            int row = (t - 256) >> 1;
            const uint4* src = (const uint4*)(Wb + row * KPAD + c * 32) + (t & 1) * 2;
            pref[0] = src[0]; pref[1] = src[1];
        }
    };
    auto commit = [&](int c) {
        if (isA) {
            u16* dst = smem + (c & 1) * 8192 + t * 32;
            *(uint4*)(dst +  0) = pref[0];
            *(uint4*)(dst +  8) = pref[1];
            *(uint4*)(dst + 16) = pref[2];
            *(uint4*)(dst + 24) = pref[3];
        } else {
            int row = (t - 256) >> 1;
            u16* dst = smem + 16384 + (c & 1) * 4096 + row * 32 + (t & 1) * 16;
            *(uint4*)(dst + 0) = pref[0];
            *(uint4*)(dst + 8) = pref[1];
        }
    };

    prefetch(0); commit(0);
    __syncthreads();

    f32x4 acc[4][4];
    #pragma unroll
    for (int i = 0; i < 4; ++i)
        #pragma unroll
        for (int j = 0; j < 4; ++j) acc[i][j] = (f32x4){0.f, 0.f, 0.f, 0.f};

    for (int c = 0; c < 9; ++c) {
        if (c < 8) prefetch(c + 1);
        const u16* Ab = smem + (c & 1) * 8192 + (R0 + lc) * 32 + quad * 8;
        const u16* Bb = smem + 16384 + (c & 1) * 4096 + (C0 + lc) * 32 + quad * 8;
        bf16x8 af[4], bfr[4];
        #pragma unroll
        for (int ti = 0; ti < 4; ++ti) af[ti]  = *(const bf16x8*)(Ab + ti * 16 * 32);
        #pragma unroll
        for (int tj = 0; tj < 4; ++tj) bfr[tj] = *(const bf16x8*)(Bb + tj * 16 * 32);
        #pragma unroll
        for (int ti = 0; ti < 4; ++ti)
            #pragma unroll
            for (int tj = 0; tj < 4; ++tj)
                acc[ti][tj] = __builtin_amdgcn_mfma_f32_16x16x32_bf16(
                    af[ti], bfr[tj], acc[ti][tj], 0, 0, 0);
        if (c < 8) { commit(c + 1); __syncthreads(); }
    }

    // bias + leaky in-place; per-channel block max (unique LDS slot per lane-col)
    #pragma unroll
    for (int tj = 0; tj < 4; ++tj) {
        const int col = C0 + tj * 16 + lc;
        const float bc = bias[col];
        float mx = 0.f;
        #pragma unroll
        for (int ti = 0; ti < 4; ++ti) {
            #pragma unroll
            for (int r = 0; r < 4; ++r) {
                float x = leaky(acc[ti][tj][r] + bc);
                acc[ti][tj][r] = x;
                mx = fmaxf(mx, x);
            }
        }
        atomicMax(&colmax_s[col], __float_as_int(mx));   // mx >= 0: int-bits OK
    }
    __syncthreads();   // colmax done + all MFMA smem reads drained
    if (t < 128) atomicMax(&ipf_out[t], colmax_s[t]);

    if (STORE_MSG) {
        // two-phase LDS transpose (128 rows x 128 ch, stride TSTR) -> coalesced uint4
        const int h = wave >> 2;        // waves 0-3 own rows 0..127; 4-7 own 128..255
        #pragma unroll
        for (int ph = 0; ph < 2; ++ph) {
            if (h == ph) {
                const int rb = R0 & 64;
                #pragma unroll
                for (int ti = 0; ti < 4; ++ti)
                    #pragma unroll
                    for (int tj = 0; tj < 4; ++tj) {
                        const int col = C0 + tj * 16 + lc;
                        #pragma unroll
                        for (int r = 0; r < 4; ++r)
                            smem[(rb + ti * 16 + quad * 4 + r) * TSTR + col]
                                = f2bf(acc[ti][tj][r]);
                    }
            }
            __syncthreads();
            #pragma unroll
            for (int i = 0; i < 4; ++i) {
                int idx = t + i * 512;          // 2048 = 128 rows x 16 uint4
                int row = idx >> 4, c16 = idx & 15;
                uint4 v = *(const uint4*)(smem + row * TSTR + c16 * 8);
                *(uint4*)(msgb + (size_t)(base + ph * 128 + row) * HD + c16 * 8) = v;
            }
            __syncthreads();
        }
    }
}

// ---------------------------------------------------------------------------
// segment max over CSR-contiguous message rows; 4 nodes per 512-thread block
// ---------------------------------------------------------------------------
__global__ __launch_bounds__(512) void segmax(
    const u16* __restrict__ msgb,   // [E,128] bf16, CSR order
    const int* __restrict__ offset, const int* __restrict__ count,
    u16* __restrict__ cf_b)         // [N,128] bf16
{
    const int n = blockIdx.x * 4 + (threadIdx.x >> 7);
    const int t = threadIdx.x & 127;
    const int off = offset[n];
    const int deg = count[n];
    float m = 0.f;
    const u16* p = msgb + (size_t)off * HD + t;
    int d = 0;
    for (; d + 1 < deg; d += 2) {
        float a = bf2f(p[(size_t)d * HD]);
        float b = bf2f(p[(size_t)(d + 1) * HD]);
        m = fmaxf(m, fmaxf(a, b));
    }
    if (d < deg) m = fmaxf(m, bf2f(p[(size_t)d * HD]));
    cf_b[(size_t)n * HD + t] = f2bf(m);
}

// ---------------------------------------------------------------------------
// fused heads: block 0 = parent_feat, block 1 = parent_geo
// ---------------------------------------------------------------------------
__global__ __launch_bounds__(128) void heads(
    const unsigned* __restrict__ ipf0_m,
    const float* __restrict__ ipf1, const float* __restrict__ ipf2,
    const float* __restrict__ secW, const float* __restrict__ secB,
    const unsigned* __restrict__ pg_m, const unsigned* __restrict__ sg_m,
    const float* __restrict__ geoW, const float* __restrict__ geoB,
    const float* __restrict__ gnw, const float* __restrict__ gnb,
    float* __restrict__ out)
{
    const int t = threadIdx.x;
    if (blockIdx.x == 0) {
        __shared__ float s[384];
        s[t]       = funmap(ipf0_m[t]);
        s[128 + t] = ipf1[t];
        s[256 + t] = ipf2[t];
        __syncthreads();
        float acc = secB[t];
        #pragma unroll 4
        for (int k = 0; k < 384; ++k) acc = fmaf(s[k], secW[t*384 + k], acc);
        out[t] = leaky(acc);
    } else {
        __shared__ float pg[128];
        __shared__ float tt[128];
        pg[t] = leaky(funmap(pg_m[t]));
        float sg = leaky(funmap(sg_m[t]));
        __syncthreads();
        float acc = geoB[t];
        #pragma unroll 4
        for (int k = 0; k < 128; ++k) acc = fmaf(pg[k], geoW[t*128 + k], acc);
        tt[t] = acc;
        __syncthreads();
        const int g = (t >> 3) << 3;
        float mu = 0.f, m2 = 0.f;
        #pragma unroll
        for (int q = 0; q < 8; ++q) { float x = tt[g + q]; mu += x; m2 += x*x; }
        mu *= 0.125f;
        m2 = m2 * 0.125f - mu * mu;
        float xn = (acc - mu) * rsqrtf(m2 + 1e-5f);
        out[128 + t] = leaky(sg + xn * gnw[t] + gnb[t]);
    }
}

// ---------------------------------------------------------------------------
extern "C" void kernel_launch(void* const* d_in, const int* in_sizes, int n_in,
                              void* d_out, int out_size, void* d_ws, size_t ws_size,
                              hipStream_t stream)
{
    const float* child_feats  = (const float*)d_in[0];
    const float* child_geo    = (const float*)d_in[1];
    const float* child_exists = (const float*)d_in[2];
    const float* etoh         = (const float*)d_in[3];
    const int*   eidx         = (const int*)  d_in[4];
    const float* op_w   = (const float*)d_in[5];
    const float* op_b   = (const float*)d_in[6];
    const float* sec_w  = (const float*)d_in[7];
    const float* sec_b  = (const float*)d_in[8];
    const float* edge_w = (const float*)d_in[9];
    const float* edge_b = (const float*)d_in[10];
    const float* geo_w  = (const float*)d_in[11];
    const float* geo_b  = (const float*)d_in[12];
    const float* sgeo_w = (const float*)d_in[13];
    const float* sgeo_b = (const float*)d_in[14];
    const float* gn_w   = (const float*)d_in[15];
    const float* gn_b   = (const float*)d_in[16];
    const float* skip_w = (const float*)d_in[17];
    const float* skip_b = (const float*)d_in[18];
    float* out = (float*)d_out;

    // workspace layout (all offsets 16B aligned)
    char* ws = (char*)d_ws;
    size_t off = 0;
    u16*   cf_a   = (u16*)(ws + off);   off += (size_t)N_NODES*HD*2;    // 5.12 MB
    u16*   cf_b   = (u16*)(ws + off);   off += (size_t)N_NODES*HD*2;    // 5.12 MB
    u16*   msgb   = (u16*)(ws + off);   off += (size_t)N_EDGES*HD*2;    // 81.92 MB
    u16*   Wb     = (u16*)(ws + off);   off += (size_t)2*128*KPAD*2;    // 147 KB
    int*   from_p = (int*)(ws + off);   off += (size_t)N_EDGES*4;       // 1.28 MB
    int*   to_p   = (int*)(ws + off);   off += (size_t)N_EDGES*4;       // 1.28 MB
    uint2* efb_p  = (uint2*)(ws + off); off += (size_t)N_EDGES*8;       // 2.56 MB
    int*   offs   = (int*)(ws + off);   off += (size_t)N_NODES*4;       // 80 KB
    char*  zero0  = ws + off;
    unsigned* ipf0_m = (unsigned*)(ws + off); off += 128*4;
    float*    ipf1   = (float*)(ws + off);    off += 128*4;
    float*    ipf2   = (float*)(ws + off);    off += 128*4;
    unsigned* pg_m   = (unsigned*)(ws + off); off += 128*4;
    unsigned* sg_m   = (unsigned*)(ws + off); off += 128*4;
    int*      count  = (int*)(ws + off);      off += (size_t)N_NODES*4;
    int*      cursor = (int*)(ws + off);      off += (size_t)N_NODES*4;
    size_t zero_bytes = (size_t)(ws + off - zero0);

    hipMemsetAsync(zero0, 0, zero_bytes, stream);

    // conv_w + histogram + encode + geo in one launch
    fused_front<<<1723, 256, 0, stream>>>(
        edge_w, Wb, eidx, count,
        child_feats, child_exists, op_w, op_b, cf_a, ipf0_m,
        child_geo, geo_w, geo_b, skip_w, skip_b, pg_m, sg_m);

    scan_offsets<<<1, 1024, 0, stream>>>(count, offs);

    fill_perm<<<N_EDGES/256, 256, 0, stream>>>(
        eidx, etoh, offs, cursor, from_p, to_p, efb_p);

    // iter 1: MFMA messages (CSR order) -> dense bf16 + column max
    edge_mfma<1><<<N_EDGES/256, 512, 0, stream>>>(
        cf_a, from_p, to_p, efb_p, Wb, edge_b, msgb, (int*)ipf1);

    // contiguous segment max -> cf_b (bf16)
    segmax<<<N_NODES/4, 512, 0, stream>>>(msgb, offs, count, cf_b);

    // iter 2: only column max needed
    edge_mfma<0><<<N_EDGES/256, 512, 0, stream>>>(
        cf_b, from_p, to_p, efb_p, Wb + 128*KPAD, edge_b + 128, nullptr, (int*)ipf2);

    heads<<<2, 128, 0, stream>>>(ipf0_m, ipf1, ipf2, sec_w, sec_b,
                                 pg_m, sg_m, sgeo_w, sgeo_b, gn_w, gn_b, out);
}